// Round 6
// baseline (447.371 us; speedup 1.0000x reference)
//
#include <hip/hip_runtime.h>
#include <cstdint>
#include <cstddef>

// Problem constants (fixed by setup_inputs)
#define BB     2
#define LL     2048
#define DMODEL 1024
#define INNER  2048
#define NST    16
#define KCONV  4
#define DRANK  64
#define MROWS  (BB*LL)   // 4096
#define SCH    64        // time chunks
#define TCH    (LL/SCH)  // 32 timesteps per chunk

typedef __attribute__((ext_vector_type(8))) _Float16 half8;   // 8 fp16 = 4 VGPRs
typedef __attribute__((ext_vector_type(4))) _Float16 half4;
typedef __attribute__((ext_vector_type(4))) float floatx4;

// async global->LDS, 16B per lane, dest = wave-uniform base + lane*16
#define GLL(gp, lp) __builtin_amdgcn_global_load_lds( \
    (const __attribute__((address_space(1))) unsigned int*)(gp), \
    (__attribute__((address_space(3))) unsigned int*)(lp), 16, 0, 0)

// ---------------------------------------------------------------------------
// One fused convert kernel: x->x16, W_in->win16, W_out->wout16,
// W_ssm->wssm16 zero-padded from 96 to 128 rows (GLL-safe for GEMM2).
// ---------------------------------------------------------------------------
__global__ __launch_bounds__(256)
void cvt_all(const float* __restrict__ x, const float* __restrict__ w_in,
             const float* __restrict__ w_out, const float* __restrict__ w_ssm,
             _Float16* __restrict__ x16, _Float16* __restrict__ win16,
             _Float16* __restrict__ wout16, _Float16* __restrict__ wssm16)
{
    const int idx = blockIdx.x * 256 + threadIdx.x;
    const int R1 = MROWS * DMODEL / 4;            // x
    const int R2 = R1 + 2 * INNER * DMODEL / 4;   // W_in
    const int R3 = R2 + DMODEL * INNER / 4;       // W_out
    const int R4 = R3 + 128 * INNER / 4;          // W_ssm (padded)
    const float* src; _Float16* dst; int i;
    if (idx < R1)      { src = x;     dst = x16;    i = idx; }
    else if (idx < R2) { src = w_in;  dst = win16;  i = idx - R1; }
    else if (idx < R3) { src = w_out; dst = wout16; i = idx - R2; }
    else if (idx < R4) {
        i = idx - R3;                               // over 128x2048/4
        const int row = i / (INNER / 4);
        half4 h = (half4){0, 0, 0, 0};
        if (row < 96) {
            const float4 v = ((const float4*)w_ssm)[i];
            h.x = (_Float16)v.x; h.y = (_Float16)v.y;
            h.z = (_Float16)v.z; h.w = (_Float16)v.w;
        }
        *(half4*)(wssm16 + (size_t)i * 4) = h;
        return;
    } else return;
    const float4 v = ((const float4*)src)[i];
    half4 h;
    h.x = (_Float16)v.x; h.y = (_Float16)v.y;
    h.z = (_Float16)v.z; h.w = (_Float16)v.w;
    *(half4*)(dst + (size_t)i * 4) = h;
}

// ---------------------------------------------------------------------------
// fp16 MFMA NT-GEMM, 64x128 tile, double-buffered LDS, one barrier/K-iter.
// 4 waves; wave w owns n-strip w (32 cols): 4x2 tiles of 16x16x32 MFMA.
// EPI 1: cols < INNER -> Cu fp16 (ld INNER); cols >= INNER -> Cg fp16
// EPI 2: atomicAdd into fp32 C (ld ldc), guard col < N
// ---------------------------------------------------------------------------
template<int EPI>
__global__ __launch_bounds__(256)
void gemm64(const _Float16* __restrict__ A, int lda,
            const _Float16* __restrict__ B, int ldb,
            float* __restrict__ C, _Float16* __restrict__ Cu,
            _Float16* __restrict__ Cg,
            int ldc, int N, int kchunk)
{
    __shared__ __align__(16) _Float16 sA[2][4 * 64 * 8];    // 4 KB each
    __shared__ __align__(16) _Float16 sB[2][4 * 128 * 8];   // 8 KB each

    const int tid  = threadIdx.x;
    const int w    = tid >> 6;        // wave 0..3 (stages k-group w; computes n-strip w)
    const int lane = tid & 63;
    const int ln15 = lane & 15;
    const int q    = lane >> 4;       // k-quad 0..3
    const int m0 = blockIdx.x * 64, n0 = blockIdx.y * 128;
    const int kbeg = blockIdx.z * kchunk;

    floatx4 acc[4][2];
    #pragma unroll
    for (int i = 0; i < 4; ++i)
        #pragma unroll
        for (int j = 0; j < 2; ++j)
            acc[i][j] = (floatx4){0.f, 0.f, 0.f, 0.f};

    const size_t a0 = (size_t)(m0 + lane) * lda + kbeg;
    const size_t b0 = (size_t)(n0 + lane) * ldb + kbeg;
    const size_t b1 = (size_t)(n0 + 64 + lane) * ldb + kbeg;
    const int aoff  = w * 64 * 8;
    const int boff0 = (w * 128 + 0) * 8;
    const int boff1 = (w * 128 + 64) * 8;

    // prologue prefetch into buffer 0
    GLL(A + a0 + w * 8, &sA[0][aoff]);
    GLL(B + b0 + w * 8, &sB[0][boff0]);
    GLL(B + b1 + w * 8, &sB[0][boff1]);

    const int niter = kchunk >> 5;
    for (int i = 0; i < niter; ++i) {
        __syncthreads();   // drains buf[i&1]'s loads (issued one compute phase ago)
        if (i + 1 < niter) {
            const int kg = (i + 1) * 32 + w * 8;
            const int nb = (i + 1) & 1;
            GLL(A + a0 + kg, &sA[nb][aoff]);
            GLL(B + b0 + kg, &sB[nb][boff0]);
            GLL(B + b1 + kg, &sB[nb][boff1]);
        }
        const _Float16* bufA = sA[i & 1];
        const _Float16* bufB = sB[i & 1];
        half8 fa[4], fb[2];
        #pragma unroll
        for (int t = 0; t < 4; ++t)
            fa[t] = *(const half8*)&bufA[(q * 64 + t * 16 + ln15) * 8];
        #pragma unroll
        for (int t = 0; t < 2; ++t)
            fb[t] = *(const half8*)&bufB[(q * 128 + w * 32 + t * 16 + ln15) * 8];
        #pragma unroll
        for (int mt = 0; mt < 4; ++mt)
            #pragma unroll
            for (int nt = 0; nt < 2; ++nt)
                acc[mt][nt] = __builtin_amdgcn_mfma_f32_16x16x32_f16(
                    fa[mt], fb[nt], acc[mt][nt], 0, 0, 0);
    }

    // epilogue: C/D layout col=lane&15, row=q*4+reg
    #pragma unroll
    for (int mt = 0; mt < 4; ++mt) {
        const int rowb = m0 + mt * 16 + q * 4;
        #pragma unroll
        for (int nt = 0; nt < 2; ++nt) {
            const int col = n0 + w * 32 + nt * 16 + ln15;
            #pragma unroll
            for (int r = 0; r < 4; ++r) {
                const float v = acc[mt][nt][r];
                const size_t row = (size_t)(rowb + r);
                if (EPI == 1) {
                    if (col < INNER) Cu[row * INNER + col] = (_Float16)v;
                    else Cg[row * INNER + (col - INNER)] = (_Float16)v;
                } else {
                    if (col < N) atomicAdd(&C[row * ldc + col], v);
                }
            }
        }
    }
}

// ---------------------------------------------------------------------------
// fp32 NT-GEMM with softplus(c + bias[col]) epilogue, fp16 output (dt GEMM).
// ---------------------------------------------------------------------------
__global__ __launch_bounds__(256)
void gemm_nt_sp(const float* __restrict__ A, int lda,
                const float* __restrict__ Bm, int ldb,
                _Float16* __restrict__ C, int ldc,
                int K, const float* __restrict__ bias)
{
    __shared__ float As[16][68];
    __shared__ float Bs[16][68];
    const int m0 = blockIdx.x * 64;
    const int n0 = blockIdx.y * 64;
    const int tid = threadIdx.x;
    const int tm = tid >> 4;
    const int tn = tid & 15;
    const int lrow = tid >> 2;
    const int lk   = (tid & 3) << 2;

    float acc[4][4] = {{0.f}};

    for (int k0 = 0; k0 < K; k0 += 16) {
        float4 a4 = *(const float4*)(A + (size_t)(m0 + lrow) * lda + (k0 + lk));
        float4 b4 = *(const float4*)(Bm + (size_t)(n0 + lrow) * ldb + (k0 + lk));
        As[lk+0][lrow] = a4.x; As[lk+1][lrow] = a4.y;
        As[lk+2][lrow] = a4.z; As[lk+3][lrow] = a4.w;
        Bs[lk+0][lrow] = b4.x; Bs[lk+1][lrow] = b4.y;
        Bs[lk+2][lrow] = b4.z; Bs[lk+3][lrow] = b4.w;
        __syncthreads();
        #pragma unroll
        for (int kk = 0; kk < 16; ++kk) {
            float4 av = *(const float4*)&As[kk][tm << 2];
            float4 bv = *(const float4*)&Bs[kk][tn << 2];
            float am[4] = {av.x, av.y, av.z, av.w};
            float bn[4] = {bv.x, bv.y, bv.z, bv.w};
            #pragma unroll
            for (int i = 0; i < 4; ++i)
                #pragma unroll
                for (int j = 0; j < 4; ++j)
                    acc[i][j] = fmaf(am[i], bn[j], acc[i][j]);
        }
        __syncthreads();
    }

    #pragma unroll
    for (int i = 0; i < 4; ++i) {
        const int row = m0 + (tm << 2) + i;
        #pragma unroll
        for (int j = 0; j < 4; ++j) {
            const int col = n0 + (tn << 2) + j;
            float v = acc[i][j] + bias[col];
            v = (v > 20.f) ? v : log1pf(__expf(v));
            C[(size_t)row * ldc + col] = (_Float16)v;
        }
    }
}

// ---------------------------------------------------------------------------
// Depthwise causal conv (k=4) on fp16 u [M, INNER], fp32 math, then SiLU.
// Emits uc16 (fp16) only. 4 channels/thread.
// ---------------------------------------------------------------------------
__global__ __launch_bounds__(256)
void conv_silu(const _Float16* __restrict__ u_in,
               const float* __restrict__ conv_w,
               _Float16* __restrict__ uc16)
{
    const int idx = blockIdx.x * 256 + threadIdx.x;  // over M*INNER/4
    const int c4 = idx & (INNER / 4 - 1);
    const int t  = (idx >> 9) & (LL - 1);
    const int bb = idx >> 20;
    const int d0 = c4 * 4;
    const size_t base = (size_t)bb * LL;

    const float4 w0 = *(const float4*)(conv_w + (d0 + 0) * KCONV);
    const float4 w1 = *(const float4*)(conv_w + (d0 + 1) * KCONV);
    const float4 w2 = *(const float4*)(conv_w + (d0 + 2) * KCONV);
    const float4 w3 = *(const float4*)(conv_w + (d0 + 3) * KCONV);
    const float wj[4][4] = {{w0.x,w0.y,w0.z,w0.w}, {w1.x,w1.y,w1.z,w1.w},
                            {w2.x,w2.y,w2.z,w2.w}, {w3.x,w3.y,w3.z,w3.w}};
    float s[4] = {0.f, 0.f, 0.f, 0.f};
    #pragma unroll
    for (int j = 0; j < KCONV; ++j) {
        const int ts = t + j - (KCONV - 1);
        if (ts >= 0) {
            const half4 v = *(const half4*)(u_in + (base + ts) * INNER + d0);
            s[0] = fmaf((float)v.x, wj[0][j], s[0]);
            s[1] = fmaf((float)v.y, wj[1][j], s[1]);
            s[2] = fmaf((float)v.z, wj[2][j], s[2]);
            s[3] = fmaf((float)v.w, wj[3][j], s[3]);
        }
    }
    half4 o16;
    o16.x = (_Float16)(s[0] / (1.f + __expf(-s[0])));
    o16.y = (_Float16)(s[1] / (1.f + __expf(-s[1])));
    o16.z = (_Float16)(s[2] / (1.f + __expf(-s[2])));
    o16.w = (_Float16)(s[3] / (1.f + __expf(-s[3])));
    *(half4*)(uc16 + (base + t) * INNER + d0) = o16;
}

// ---------------------------------------------------------------------------
// Scan pass 1: per-chunk summaries (h[16] in registers per thread-channel).
// u/dt read as fp16; state math fp32.
// ---------------------------------------------------------------------------
__global__ __launch_bounds__(256)
void scan_pass1(const _Float16* __restrict__ uc16,
                const _Float16* __restrict__ dt16,
                const float* __restrict__ params,
                const float* __restrict__ log_A,
                float* __restrict__ Hout,
                float* __restrict__ sumdt_out)
{
    const int bid = blockIdx.x;
    const int c   = bid & (SCH - 1);
    const int cg  = (bid >> 6) & 7;
    const int b   = bid >> 9;
    const int tid = threadIdx.x;
    const int d   = cg * 256 + tid;
    const size_t rowbase = (size_t)b * LL + (size_t)c * TCH;

    float A[NST];
    #pragma unroll
    for (int n = 0; n < NST; n += 4) {
        float4 v = *(const float4*)(log_A + (size_t)d * NST + n);
        A[n+0] = -__expf(v.x); A[n+1] = -__expf(v.y);
        A[n+2] = -__expf(v.z); A[n+3] = -__expf(v.w);
    }

    __shared__ float Bs[TCH * NST];
    for (int i = tid; i < TCH * NST; i += 256) {
        const int t = i >> 4, j = i & 15;
        Bs[i] = params[(rowbase + t) * 96 + DRANK + j];
    }
    __syncthreads();

    float h[NST];
    #pragma unroll
    for (int n = 0; n < NST; ++n) h[n] = 0.f;
    float sdt = 0.f;

    #pragma unroll 4
    for (int t = 0; t < TCH; ++t) {
        const float dtv = (float)dt16[(rowbase + t) * INNER + d];
        const float uv  = (float)uc16[(rowbase + t) * INNER + d];
        const float du = dtv * uv;
        sdt += dtv;
        const float4* Bp = (const float4*)&Bs[t * NST];
        const float4 B0 = Bp[0], B1 = Bp[1], B2 = Bp[2], B3 = Bp[3];
        const float Bv[NST] = {B0.x,B0.y,B0.z,B0.w, B1.x,B1.y,B1.z,B1.w,
                               B2.x,B2.y,B2.z,B2.w, B3.x,B3.y,B3.z,B3.w};
        #pragma unroll
        for (int n = 0; n < NST; ++n)
            h[n] = fmaf(__expf(dtv * A[n]), h[n], du * Bv[n]);
    }

    const size_t o = ((size_t)(b * SCH + c) * INNER + d) * NST;
    #pragma unroll
    for (int n = 0; n < NST; n += 4)
        *(float4*)(Hout + o + n) = make_float4(h[n], h[n+1], h[n+2], h[n+3]);
    sumdt_out[(size_t)(b * SCH + c) * INNER + d] = sdt;
}

// ---------------------------------------------------------------------------
// Scan pass 2: serial combine over chunks. One thread = one (b,d,n).
// ---------------------------------------------------------------------------
__global__ __launch_bounds__(256)
void scan_pass2(const float* __restrict__ Hbuf,
                const float* __restrict__ sumdt,
                const float* __restrict__ log_A,
                float* __restrict__ hinit)
{
    const int idx = blockIdx.x * 256 + threadIdx.x;
    const int n = idx & 15;
    const int d = (idx >> 4) & (INNER - 1);
    const int b = idx >> 15;
    const float An = -__expf(log_A[(size_t)d * NST + n]);
    float h = 0.f;
    for (int c = 0; c < SCH; ++c) {
        const size_t o = ((size_t)(b * SCH + c) * INNER + d) * NST + n;
        hinit[o] = h;
        const float P = __expf(An * sumdt[(size_t)(b * SCH + c) * INNER + d]);
        h = Hbuf[o] + P * h;
    }
}

// ---------------------------------------------------------------------------
// Scan pass 3: re-scan each chunk from h_init, fused epilogue:
// yg = (y + u*D) * silu(gate) -> fp16 (feeds GEMM3).
// ---------------------------------------------------------------------------
__global__ __launch_bounds__(256)
void scan_pass3(const _Float16* __restrict__ uc16,
                const _Float16* __restrict__ dt16,
                const float* __restrict__ params,
                const _Float16* __restrict__ gate16,  // [M, INNER]
                const float* __restrict__ log_A,
                const float* __restrict__ Dv,
                const float* __restrict__ hinit,
                _Float16* __restrict__ yg16)          // [M, INNER]
{
    const int bid = blockIdx.x;
    const int c   = bid & (SCH - 1);
    const int cg  = (bid >> 6) & 7;
    const int b   = bid >> 9;
    const int tid = threadIdx.x;
    const int d   = cg * 256 + tid;
    const size_t rowbase = (size_t)b * LL + (size_t)c * TCH;

    float A[NST];
    #pragma unroll
    for (int n = 0; n < NST; n += 4) {
        float4 v = *(const float4*)(log_A + (size_t)d * NST + n);
        A[n+0] = -__expf(v.x); A[n+1] = -__expf(v.y);
        A[n+2] = -__expf(v.z); A[n+3] = -__expf(v.w);
    }
    const float Dd = Dv[d];

    __shared__ float BCs[TCH * 32];
    for (int i = tid; i < TCH * 32; i += 256) {
        const int t = i >> 5, j = i & 31;
        BCs[i] = params[(rowbase + t) * 96 + DRANK + j];
    }

    float h[NST];
    {
        const size_t o = ((size_t)(b * SCH + c) * INNER + d) * NST;
        #pragma unroll
        for (int n = 0; n < NST; n += 4) {
            float4 v = *(const float4*)(hinit + o + n);
            h[n] = v.x; h[n+1] = v.y; h[n+2] = v.z; h[n+3] = v.w;
        }
    }
    __syncthreads();

    #pragma unroll 2
    for (int t = 0; t < TCH; ++t) {
        const float dtv = (float)dt16[(rowbase + t) * INNER + d];
        const float uv  = (float)uc16[(rowbase + t) * INNER + d];
        const float gv  = (float)gate16[(rowbase + t) * INNER + d];
        const float du = dtv * uv;
        const float4* Bp = (const float4*)&BCs[t * 32];
        const float4 B0 = Bp[0], B1 = Bp[1], B2 = Bp[2], B3 = Bp[3];
        const float4 C0 = Bp[4], C1 = Bp[5], C2 = Bp[6], C3 = Bp[7];
        const float Bv[NST] = {B0.x,B0.y,B0.z,B0.w, B1.x,B1.y,B1.z,B1.w,
                               B2.x,B2.y,B2.z,B2.w, B3.x,B3.y,B3.z,B3.w};
        const float Cv[NST] = {C0.x,C0.y,C0.z,C0.w, C1.x,C1.y,C1.z,C1.w,
                               C2.x,C2.y,C2.z,C2.w, C3.x,C3.y,C3.z,C3.w};
        #pragma unroll
        for (int n = 0; n < NST; ++n)
            h[n] = fmaf(__expf(dtv * A[n]), h[n], du * Bv[n]);
        float p[8];
        #pragma unroll
        for (int n = 0; n < 8; ++n)
            p[n] = fmaf(h[n], Cv[n], h[n+8] * Cv[n+8]);
        const float y = ((p[0]+p[1]) + (p[2]+p[3])) + ((p[4]+p[5]) + (p[6]+p[7]));
        const float sg = gv / (1.f + __expf(-gv));
        yg16[(rowbase + t) * INNER + d] = (_Float16)((y + uv * Dd) * sg);
    }
}

// ---------------------------------------------------------------------------
extern "C" void kernel_launch(void* const* d_in, const int* in_sizes, int n_in,
                              void* d_out, int out_size, void* d_ws, size_t ws_size,
                              hipStream_t stream)
{
    const float* x     = (const float*)d_in[0];
    const float* W_in  = (const float*)d_in[1];
    const float* convw = (const float*)d_in[2];
    const float* W_ssm = (const float*)d_in[3];
    const float* W_dt  = (const float*)d_in[4];
    const float* b_dt  = (const float*)d_in[5];
    const float* log_A = (const float*)d_in[6];
    const float* Dv    = (const float*)d_in[7];
    const float* W_out = (const float*)d_in[8];
    float* out = (float*)d_out;

    float* ws = (float*)d_ws;
    float* params = ws;                                       // 393216
    float* Hbuf   = params + (size_t)MROWS * 96;              // 4.2M
    float* hinit  = Hbuf   + (size_t)BB * SCH * INNER * NST;  // 4.2M
    float* sumdt  = hinit  + (size_t)BB * SCH * INNER * NST;  // 262144
    _Float16* x16    = (_Float16*)(sumdt + (size_t)BB * SCH * INNER);
    _Float16* win16  = x16    + (size_t)MROWS * DMODEL;
    _Float16* wout16 = win16  + (size_t)(2 * INNER) * DMODEL;
    _Float16* wssm16 = wout16 + (size_t)DMODEL * INNER;       // 128 x 2048 (padded)
    _Float16* u16raw = wssm16 + (size_t)128 * INNER;          // GEMM1 u-half
    _Float16* gate16 = u16raw + (size_t)MROWS * INNER;
    _Float16* uc16   = gate16 + (size_t)MROWS * INNER;        // conv+silu output
    _Float16* dt16   = uc16   + (size_t)MROWS * INNER;
    _Float16* yg16   = dt16   + (size_t)MROWS * INNER;

    // zero accumulators for split-K atomics
    hipMemsetAsync(params, 0, (size_t)MROWS * 96 * sizeof(float), stream);
    hipMemsetAsync(out, 0, (size_t)MROWS * DMODEL * sizeof(float), stream);

    // 0. all fp32->fp16 converts (+ W_ssm zero-pad to 128 rows)
    {
        const int total4 = MROWS * DMODEL / 4 + 2 * INNER * DMODEL / 4 +
                           DMODEL * INNER / 4 + 128 * INNER / 4;
        cvt_all<<<(total4 + 255) / 256, 256, 0, stream>>>(
            x, W_in, W_out, W_ssm, x16, win16, wout16, wssm16);
    }

    // 1. xz = x @ W_in.T -> u16raw | gate16   M=4096 N=4096 K=1024
    gemm64<1><<<dim3(64, 32, 1), 256, 0, stream>>>(
        x16, DMODEL, win16, DMODEL, nullptr, u16raw, gate16,
        0, 2 * INNER, DMODEL);

    // 2. uc16 = silu(causal_conv(u16raw))
    conv_silu<<<(MROWS * INNER / 4) / 256, 256, 0, stream>>>(
        u16raw, convw, uc16);

    // 3. params = uc16 @ wssm16.T  (split-K x8, atomic)  N=96
    gemm64<2><<<dim3(64, 1, 8), 256, 0, stream>>>(
        uc16, INNER, wssm16, INNER, params, nullptr, nullptr,
        96, 96, INNER / 8);

    // 4. dt16 = softplus(d_low @ W_dt.T + b_dt)  M=4096 N=2048 K=64 (lda=96)
    gemm_nt_sp<<<dim3(64, 32), 256, 0, stream>>>(
        params, 96, W_dt, DRANK, dt16, INNER, DRANK, b_dt);

    // 5. chunked selective scan (3 passes); pass3 emits fp16 yg
    scan_pass1<<<BB * (INNER / 256) * SCH, 256, 0, stream>>>(
        uc16, dt16, params, log_A, Hbuf, sumdt);
    scan_pass2<<<BB * INNER * NST / 256, 256, 0, stream>>>(
        Hbuf, sumdt, log_A, hinit);
    scan_pass3<<<BB * (INNER / 256) * SCH, 256, 0, stream>>>(
        uc16, dt16, params, gate16, log_A, Dv, hinit, yg16);

    // 6. out = yg @ W_out.T  (split-K x2, atomic)  N=1024
    gemm64<2><<<dim3(64, 8, 2), 256, 0, stream>>>(
        yg16, INNER, wout16, INNER, out, nullptr, nullptr,
        DMODEL, DMODEL, INNER / 2);
}

// Round 7
// 420.604 us; speedup vs baseline: 1.0636x; 1.0636x over previous
//
#include <hip/hip_runtime.h>
#include <cstdint>
#include <cstddef>

// Problem constants (fixed by setup_inputs)
#define BB     2
#define LL     2048
#define DMODEL 1024
#define INNER  2048
#define NST    16
#define KCONV  4
#define DRANK  64
#define MROWS  (BB*LL)   // 4096
#define SCH    64        // time chunks
#define TCH    (LL/SCH)  // 32 timesteps per chunk

typedef __attribute__((ext_vector_type(8))) _Float16 half8;   // 8 fp16 = 4 VGPRs
typedef __attribute__((ext_vector_type(4))) _Float16 half4;
typedef __attribute__((ext_vector_type(4))) float floatx4;

// async global->LDS, 16B per lane, dest = wave-uniform base + lane*16
#define GLL(gp, lp) __builtin_amdgcn_global_load_lds( \
    (const __attribute__((address_space(1))) unsigned int*)(gp), \
    (__attribute__((address_space(3))) unsigned int*)(lp), 16, 0, 0)

// ---------------------------------------------------------------------------
// One fused convert kernel: x->x16, W_in->win16, W_out->wout16,
// W_ssm->wssm16 zero-padded from 96 to 128 rows (GLL-safe for GEMM2).
// ---------------------------------------------------------------------------
__global__ __launch_bounds__(256)
void cvt_all(const float* __restrict__ x, const float* __restrict__ w_in,
             const float* __restrict__ w_out, const float* __restrict__ w_ssm,
             _Float16* __restrict__ x16, _Float16* __restrict__ win16,
             _Float16* __restrict__ wout16, _Float16* __restrict__ wssm16)
{
    const int idx = blockIdx.x * 256 + threadIdx.x;
    const int R1 = MROWS * DMODEL / 4;            // x
    const int R2 = R1 + 2 * INNER * DMODEL / 4;   // W_in
    const int R3 = R2 + DMODEL * INNER / 4;       // W_out
    const int R4 = R3 + 128 * INNER / 4;          // W_ssm (padded)
    const float* src; _Float16* dst; int i;
    if (idx < R1)      { src = x;     dst = x16;    i = idx; }
    else if (idx < R2) { src = w_in;  dst = win16;  i = idx - R1; }
    else if (idx < R3) { src = w_out; dst = wout16; i = idx - R2; }
    else if (idx < R4) {
        i = idx - R3;                               // over 128x2048/4
        const int row = i / (INNER / 4);
        half4 h = (half4){0, 0, 0, 0};
        if (row < 96) {
            const float4 v = ((const float4*)w_ssm)[i];
            h.x = (_Float16)v.x; h.y = (_Float16)v.y;
            h.z = (_Float16)v.z; h.w = (_Float16)v.w;
        }
        *(half4*)(wssm16 + (size_t)i * 4) = h;
        return;
    } else return;
    const float4 v = ((const float4*)src)[i];
    half4 h;
    h.x = (_Float16)v.x; h.y = (_Float16)v.y;
    h.z = (_Float16)v.z; h.w = (_Float16)v.w;
    *(half4*)(dst + (size_t)i * 4) = h;
}

// ---------------------------------------------------------------------------
// fp16 MFMA NT-GEMM, 128x128 tile, double-buffered LDS, one barrier/K-iter.
// 4 waves, each 4x4 tiles of mfma_f32_16x16x32_f16, BK=32.
// SWZ=1: XCD-aware block mapping. Blocks go to XCD (blockIdx.x % 8); we give
// XCD k only n-blocks with n_blk % 8 == k, m iterating fastest, so each
// XCD's B working set (<=4 n-tiles = 1 MB) stays resident in its 4 MB L2.
// EPI 1: cols < INNER -> Cu fp16; cols >= INNER -> Cg fp16 (both ld INNER)
// EPI 2: atomicAdd into fp32 C (ld ldc), guard col < N
// ---------------------------------------------------------------------------
template<int EPI, int SWZ>
__global__ __launch_bounds__(256)
void gemm128(const _Float16* __restrict__ A, int lda,
             const _Float16* __restrict__ B, int ldb,
             float* __restrict__ C, _Float16* __restrict__ Cu,
             _Float16* __restrict__ Cg,
             int ldc, int N, int kchunk, int nMblk)
{
    __shared__ __align__(16) _Float16 sA[2][4 * 128 * 8];  // 8 KB each
    __shared__ __align__(16) _Float16 sB[2][4 * 128 * 8];

    int m_blk, n_blk;
    if (SWZ) {
        const int L = blockIdx.x;
        const int xcd = L & 7;
        const int t = L >> 3;
        m_blk = t % nMblk;
        n_blk = xcd + 8 * (t / nMblk);
    } else {
        m_blk = blockIdx.x;
        n_blk = blockIdx.y;
    }
    const int m0 = m_blk * 128, n0 = n_blk * 128;
    const int kbeg = blockIdx.z * kchunk;

    const int tid  = threadIdx.x;
    const int w    = tid >> 6;        // wave 0..3 (owns k-group w)
    const int lane = tid & 63;
    const int ln15 = lane & 15;
    const int q    = lane >> 4;       // k-quad 0..3
    const int wm   = w & 1, wn = w >> 1;

    floatx4 acc[4][4];
    #pragma unroll
    for (int i = 0; i < 4; ++i)
        #pragma unroll
        for (int j = 0; j < 4; ++j)
            acc[i][j] = (floatx4){0.f, 0.f, 0.f, 0.f};

    const size_t a0 = (size_t)(m0 + lane) * lda + kbeg;
    const size_t a1 = (size_t)(m0 + 64 + lane) * lda + kbeg;
    const size_t b0 = (size_t)(n0 + lane) * ldb + kbeg;
    const size_t b1 = (size_t)(n0 + 64 + lane) * ldb + kbeg;
    const int wo0 = (w * 128 + 0) * 8, wo1 = (w * 128 + 64) * 8;

    // prologue prefetch into buffer 0
    {
        const int kg = w * 8;
        GLL(A + a0 + kg, &sA[0][wo0]);
        GLL(A + a1 + kg, &sA[0][wo1]);
        GLL(B + b0 + kg, &sB[0][wo0]);
        GLL(B + b1 + kg, &sB[0][wo1]);
    }

    const int niter = kchunk >> 5;
    for (int i = 0; i < niter; ++i) {
        __syncthreads();   // drains buf[i&1]'s loads (issued one compute phase ago)
        if (i + 1 < niter) {
            const int kg = (i + 1) * 32 + w * 8;
            const int nb = (i + 1) & 1;
            GLL(A + a0 + kg, &sA[nb][wo0]);
            GLL(A + a1 + kg, &sA[nb][wo1]);
            GLL(B + b0 + kg, &sB[nb][wo0]);
            GLL(B + b1 + kg, &sB[nb][wo1]);
        }
        const _Float16* bufA = sA[i & 1];
        const _Float16* bufB = sB[i & 1];
        half8 fa[4], fb[4];
        #pragma unroll
        for (int t = 0; t < 4; ++t) {
            fa[t] = *(const half8*)&bufA[(q * 128 + wm * 64 + t * 16 + ln15) * 8];
            fb[t] = *(const half8*)&bufB[(q * 128 + wn * 64 + t * 16 + ln15) * 8];
        }
        #pragma unroll
        for (int mt = 0; mt < 4; ++mt)
            #pragma unroll
            for (int nt = 0; nt < 4; ++nt)
                acc[mt][nt] = __builtin_amdgcn_mfma_f32_16x16x32_f16(
                    fa[mt], fb[nt], acc[mt][nt], 0, 0, 0);
    }

    // epilogue: C/D layout col=lane&15, row=q*4+reg
    #pragma unroll
    for (int mt = 0; mt < 4; ++mt) {
        const int rowb = m0 + wm * 64 + mt * 16 + q * 4;
        #pragma unroll
        for (int nt = 0; nt < 4; ++nt) {
            const int col = n0 + wn * 64 + nt * 16 + ln15;
            #pragma unroll
            for (int r = 0; r < 4; ++r) {
                const float v = acc[mt][nt][r];
                const size_t row = (size_t)(rowb + r);
                if (EPI == 1) {
                    if (col < INNER) Cu[row * INNER + col] = (_Float16)v;
                    else Cg[row * INNER + (col - INNER)] = (_Float16)v;
                } else {
                    if (col < N) atomicAdd(&C[row * ldc + col], v);
                }
            }
        }
    }
}

// ---------------------------------------------------------------------------
// fp32 NT-GEMM with softplus(c + bias[col]) epilogue, fp16 output (dt GEMM).
// ---------------------------------------------------------------------------
__global__ __launch_bounds__(256)
void gemm_nt_sp(const float* __restrict__ A, int lda,
                const float* __restrict__ Bm, int ldb,
                _Float16* __restrict__ C, int ldc,
                int K, const float* __restrict__ bias)
{
    __shared__ float As[16][68];
    __shared__ float Bs[16][68];
    const int m0 = blockIdx.x * 64;
    const int n0 = blockIdx.y * 64;
    const int tid = threadIdx.x;
    const int tm = tid >> 4;
    const int tn = tid & 15;
    const int lrow = tid >> 2;
    const int lk   = (tid & 3) << 2;

    float acc[4][4] = {{0.f}};

    for (int k0 = 0; k0 < K; k0 += 16) {
        float4 a4 = *(const float4*)(A + (size_t)(m0 + lrow) * lda + (k0 + lk));
        float4 b4 = *(const float4*)(Bm + (size_t)(n0 + lrow) * ldb + (k0 + lk));
        As[lk+0][lrow] = a4.x; As[lk+1][lrow] = a4.y;
        As[lk+2][lrow] = a4.z; As[lk+3][lrow] = a4.w;
        Bs[lk+0][lrow] = b4.x; Bs[lk+1][lrow] = b4.y;
        Bs[lk+2][lrow] = b4.z; Bs[lk+3][lrow] = b4.w;
        __syncthreads();
        #pragma unroll
        for (int kk = 0; kk < 16; ++kk) {
            float4 av = *(const float4*)&As[kk][tm << 2];
            float4 bv = *(const float4*)&Bs[kk][tn << 2];
            float am[4] = {av.x, av.y, av.z, av.w};
            float bn[4] = {bv.x, bv.y, bv.z, bv.w};
            #pragma unroll
            for (int i = 0; i < 4; ++i)
                #pragma unroll
                for (int j = 0; j < 4; ++j)
                    acc[i][j] = fmaf(am[i], bn[j], acc[i][j]);
        }
        __syncthreads();
    }

    #pragma unroll
    for (int i = 0; i < 4; ++i) {
        const int row = m0 + (tm << 2) + i;
        #pragma unroll
        for (int j = 0; j < 4; ++j) {
            const int col = n0 + (tn << 2) + j;
            float v = acc[i][j] + bias[col];
            v = (v > 20.f) ? v : log1pf(__expf(v));
            C[(size_t)row * ldc + col] = (_Float16)v;
        }
    }
}

// ---------------------------------------------------------------------------
// Depthwise causal conv (k=4) on fp16 u [M, INNER], fp32 math, then SiLU.
// ---------------------------------------------------------------------------
__global__ __launch_bounds__(256)
void conv_silu(const _Float16* __restrict__ u_in,
               const float* __restrict__ conv_w,
               _Float16* __restrict__ uc16)
{
    const int idx = blockIdx.x * 256 + threadIdx.x;  // over M*INNER/4
    const int c4 = idx & (INNER / 4 - 1);
    const int t  = (idx >> 9) & (LL - 1);
    const int bb = idx >> 20;
    const int d0 = c4 * 4;
    const size_t base = (size_t)bb * LL;

    const float4 w0 = *(const float4*)(conv_w + (d0 + 0) * KCONV);
    const float4 w1 = *(const float4*)(conv_w + (d0 + 1) * KCONV);
    const float4 w2 = *(const float4*)(conv_w + (d0 + 2) * KCONV);
    const float4 w3 = *(const float4*)(conv_w + (d0 + 3) * KCONV);
    const float wj[4][4] = {{w0.x,w0.y,w0.z,w0.w}, {w1.x,w1.y,w1.z,w1.w},
                            {w2.x,w2.y,w2.z,w2.w}, {w3.x,w3.y,w3.z,w3.w}};
    float s[4] = {0.f, 0.f, 0.f, 0.f};
    #pragma unroll
    for (int j = 0; j < KCONV; ++j) {
        const int ts = t + j - (KCONV - 1);
        if (ts >= 0) {
            const half4 v = *(const half4*)(u_in + (base + ts) * INNER + d0);
            s[0] = fmaf((float)v.x, wj[0][j], s[0]);
            s[1] = fmaf((float)v.y, wj[1][j], s[1]);
            s[2] = fmaf((float)v.z, wj[2][j], s[2]);
            s[3] = fmaf((float)v.w, wj[3][j], s[3]);
        }
    }
    half4 o16;
    o16.x = (_Float16)(s[0] / (1.f + __expf(-s[0])));
    o16.y = (_Float16)(s[1] / (1.f + __expf(-s[1])));
    o16.z = (_Float16)(s[2] / (1.f + __expf(-s[2])));
    o16.w = (_Float16)(s[3] / (1.f + __expf(-s[3])));
    *(half4*)(uc16 + (base + t) * INNER + d0) = o16;
}

// ---------------------------------------------------------------------------
// Scan pass 1: per-chunk summaries (h[16] in registers per thread-channel).
// ---------------------------------------------------------------------------
__global__ __launch_bounds__(256)
void scan_pass1(const _Float16* __restrict__ uc16,
                const _Float16* __restrict__ dt16,
                const float* __restrict__ params,
                const float* __restrict__ log_A,
                float* __restrict__ Hout,
                float* __restrict__ sumdt_out)
{
    const int bid = blockIdx.x;
    const int c   = bid & (SCH - 1);
    const int cg  = (bid >> 6) & 7;
    const int b   = bid >> 9;
    const int tid = threadIdx.x;
    const int d   = cg * 256 + tid;
    const size_t rowbase = (size_t)b * LL + (size_t)c * TCH;

    float A[NST];
    #pragma unroll
    for (int n = 0; n < NST; n += 4) {
        float4 v = *(const float4*)(log_A + (size_t)d * NST + n);
        A[n+0] = -__expf(v.x); A[n+1] = -__expf(v.y);
        A[n+2] = -__expf(v.z); A[n+3] = -__expf(v.w);
    }

    __shared__ float Bs[TCH * NST];
    for (int i = tid; i < TCH * NST; i += 256) {
        const int t = i >> 4, j = i & 15;
        Bs[i] = params[(rowbase + t) * 96 + DRANK + j];
    }
    __syncthreads();

    float h[NST];
    #pragma unroll
    for (int n = 0; n < NST; ++n) h[n] = 0.f;
    float sdt = 0.f;

    #pragma unroll 4
    for (int t = 0; t < TCH; ++t) {
        const float dtv = (float)dt16[(rowbase + t) * INNER + d];
        const float uv  = (float)uc16[(rowbase + t) * INNER + d];
        const float du = dtv * uv;
        sdt += dtv;
        const float4* Bp = (const float4*)&Bs[t * NST];
        const float4 B0 = Bp[0], B1 = Bp[1], B2 = Bp[2], B3 = Bp[3];
        const float Bv[NST] = {B0.x,B0.y,B0.z,B0.w, B1.x,B1.y,B1.z,B1.w,
                               B2.x,B2.y,B2.z,B2.w, B3.x,B3.y,B3.z,B3.w};
        #pragma unroll
        for (int n = 0; n < NST; ++n)
            h[n] = fmaf(__expf(dtv * A[n]), h[n], du * Bv[n]);
    }

    const size_t o = ((size_t)(b * SCH + c) * INNER + d) * NST;
    #pragma unroll
    for (int n = 0; n < NST; n += 4)
        *(float4*)(Hout + o + n) = make_float4(h[n], h[n+1], h[n+2], h[n+3]);
    sumdt_out[(size_t)(b * SCH + c) * INNER + d] = sdt;
}

// ---------------------------------------------------------------------------
// Scan pass 2: serial combine over chunks. One thread = one (b,d,n).
// ---------------------------------------------------------------------------
__global__ __launch_bounds__(256)
void scan_pass2(const float* __restrict__ Hbuf,
                const float* __restrict__ sumdt,
                const float* __restrict__ log_A,
                float* __restrict__ hinit)
{
    const int idx = blockIdx.x * 256 + threadIdx.x;
    const int n = idx & 15;
    const int d = (idx >> 4) & (INNER - 1);
    const int b = idx >> 15;
    const float An = -__expf(log_A[(size_t)d * NST + n]);
    float h = 0.f;
    for (int c = 0; c < SCH; ++c) {
        const size_t o = ((size_t)(b * SCH + c) * INNER + d) * NST + n;
        hinit[o] = h;
        const float P = __expf(An * sumdt[(size_t)(b * SCH + c) * INNER + d]);
        h = Hbuf[o] + P * h;
    }
}

// ---------------------------------------------------------------------------
// Scan pass 3: re-scan each chunk from h_init, fused epilogue:
// yg = (y + u*D) * silu(gate) -> fp16 (feeds GEMM3).
// ---------------------------------------------------------------------------
__global__ __launch_bounds__(256)
void scan_pass3(const _Float16* __restrict__ uc16,
                const _Float16* __restrict__ dt16,
                const float* __restrict__ params,
                const _Float16* __restrict__ gate16,  // [M, INNER]
                const float* __restrict__ log_A,
                const float* __restrict__ Dv,
                const float* __restrict__ hinit,
                _Float16* __restrict__ yg16)          // [M, INNER]
{
    const int bid = blockIdx.x;
    const int c   = bid & (SCH - 1);
    const int cg  = (bid >> 6) & 7;
    const int b   = bid >> 9;
    const int tid = threadIdx.x;
    const int d   = cg * 256 + tid;
    const size_t rowbase = (size_t)b * LL + (size_t)c * TCH;

    float A[NST];
    #pragma unroll
    for (int n = 0; n < NST; n += 4) {
        float4 v = *(const float4*)(log_A + (size_t)d * NST + n);
        A[n+0] = -__expf(v.x); A[n+1] = -__expf(v.y);
        A[n+2] = -__expf(v.z); A[n+3] = -__expf(v.w);
    }
    const float Dd = Dv[d];

    __shared__ float BCs[TCH * 32];
    for (int i = tid; i < TCH * 32; i += 256) {
        const int t = i >> 5, j = i & 31;
        BCs[i] = params[(rowbase + t) * 96 + DRANK + j];
    }

    float h[NST];
    {
        const size_t o = ((size_t)(b * SCH + c) * INNER + d) * NST;
        #pragma unroll
        for (int n = 0; n < NST; n += 4) {
            float4 v = *(const float4*)(hinit + o + n);
            h[n] = v.x; h[n+1] = v.y; h[n+2] = v.z; h[n+3] = v.w;
        }
    }
    __syncthreads();

    #pragma unroll 2
    for (int t = 0; t < TCH; ++t) {
        const float dtv = (float)dt16[(rowbase + t) * INNER + d];
        const float uv  = (float)uc16[(rowbase + t) * INNER + d];
        const float gv  = (float)gate16[(rowbase + t) * INNER + d];
        const float du = dtv * uv;
        const float4* Bp = (const float4*)&BCs[t * 32];
        const float4 B0 = Bp[0], B1 = Bp[1], B2 = Bp[2], B3 = Bp[3];
        const float4 C0 = Bp[4], C1 = Bp[5], C2 = Bp[6], C3 = Bp[7];
        const float Bv[NST] = {B0.x,B0.y,B0.z,B0.w, B1.x,B1.y,B1.z,B1.w,
                               B2.x,B2.y,B2.z,B2.w, B3.x,B3.y,B3.z,B3.w};
        const float Cv[NST] = {C0.x,C0.y,C0.z,C0.w, C1.x,C1.y,C1.z,C1.w,
                               C2.x,C2.y,C2.z,C2.w, C3.x,C3.y,C3.z,C3.w};
        #pragma unroll
        for (int n = 0; n < NST; ++n)
            h[n] = fmaf(__expf(dtv * A[n]), h[n], du * Bv[n]);
        float p[8];
        #pragma unroll
        for (int n = 0; n < 8; ++n)
            p[n] = fmaf(h[n], Cv[n], h[n+8] * Cv[n+8]);
        const float y = ((p[0]+p[1]) + (p[2]+p[3])) + ((p[4]+p[5]) + (p[6]+p[7]));
        const float sg = gv / (1.f + __expf(-gv));
        yg16[(rowbase + t) * INNER + d] = (_Float16)((y + uv * Dd) * sg);
    }
}

// ---------------------------------------------------------------------------
extern "C" void kernel_launch(void* const* d_in, const int* in_sizes, int n_in,
                              void* d_out, int out_size, void* d_ws, size_t ws_size,
                              hipStream_t stream)
{
    const float* x     = (const float*)d_in[0];
    const float* W_in  = (const float*)d_in[1];
    const float* convw = (const float*)d_in[2];
    const float* W_ssm = (const float*)d_in[3];
    const float* W_dt  = (const float*)d_in[4];
    const float* b_dt  = (const float*)d_in[5];
    const float* log_A = (const float*)d_in[6];
    const float* Dv    = (const float*)d_in[7];
    const float* W_out = (const float*)d_in[8];
    float* out = (float*)d_out;

    float* ws = (float*)d_ws;
    float* params = ws;                                       // 393216
    float* Hbuf   = params + (size_t)MROWS * 96;              // 4.2M
    float* hinit  = Hbuf   + (size_t)BB * SCH * INNER * NST;  // 4.2M
    float* sumdt  = hinit  + (size_t)BB * SCH * INNER * NST;  // 262144
    _Float16* x16    = (_Float16*)(sumdt + (size_t)BB * SCH * INNER);
    _Float16* win16  = x16    + (size_t)MROWS * DMODEL;
    _Float16* wout16 = win16  + (size_t)(2 * INNER) * DMODEL;
    _Float16* wssm16 = wout16 + (size_t)DMODEL * INNER;       // 128 x 2048 (padded)
    _Float16* u16raw = wssm16 + (size_t)128 * INNER;          // GEMM1 u-half
    _Float16* gate16 = u16raw + (size_t)MROWS * INNER;
    _Float16* uc16   = gate16 + (size_t)MROWS * INNER;        // conv+silu output
    _Float16* dt16   = uc16   + (size_t)MROWS * INNER;
    _Float16* yg16   = dt16   + (size_t)MROWS * INNER;

    // zero accumulators for split-K atomics
    hipMemsetAsync(params, 0, (size_t)MROWS * 96 * sizeof(float), stream);
    hipMemsetAsync(out, 0, (size_t)MROWS * DMODEL * sizeof(float), stream);

    // 0. all fp32->fp16 converts (+ W_ssm zero-pad to 128 rows)
    {
        const int total4 = MROWS * DMODEL / 4 + 2 * INNER * DMODEL / 4 +
                           DMODEL * INNER / 4 + 128 * INNER / 4;
        cvt_all<<<(total4 + 255) / 256, 256, 0, stream>>>(
            x, W_in, W_out, W_ssm, x16, win16, wout16, wssm16);
    }

    // 1. xz = x @ W_in.T -> u16raw | gate16   M=4096 N=4096 K=1024
    //    1024 blocks, XCD-swizzled (32 m-blocks fastest, 4 n-groups / XCD)
    gemm128<1, 1><<<dim3(1024, 1, 1), 256, 0, stream>>>(
        x16, DMODEL, win16, DMODEL, nullptr, u16raw, gate16,
        0, 2 * INNER, DMODEL, 32);

    // 2. uc16 = silu(causal_conv(u16raw))
    conv_silu<<<(MROWS * INNER / 4) / 256, 256, 0, stream>>>(
        u16raw, convw, uc16);

    // 3. params = uc16 @ wssm16.T  (split-K x8, atomic)  N=96 (tile covers 128)
    gemm128<2, 0><<<dim3(32, 1, 8), 256, 0, stream>>>(
        uc16, INNER, wssm16, INNER, params, nullptr, nullptr,
        96, 96, INNER / 8, 32);

    // 4. dt16 = softplus(d_low @ W_dt.T + b_dt)  M=4096 N=2048 K=64 (lda=96)
    gemm_nt_sp<<<dim3(64, 32), 256, 0, stream>>>(
        params, 96, W_dt, DRANK, dt16, INNER, DRANK, b_dt);

    // 5. chunked selective scan (3 passes); pass3 emits fp16 yg
    scan_pass1<<<BB * (INNER / 256) * SCH, 256, 0, stream>>>(
        uc16, dt16, params, log_A, Hbuf, sumdt);
    scan_pass2<<<BB * INNER * NST / 256, 256, 0, stream>>>(
        Hbuf, sumdt, log_A, hinit);
    scan_pass3<<<BB * (INNER / 256) * SCH, 256, 0, stream>>>(
        uc16, dt16, params, gate16, log_A, Dv, hinit, yg16);

    // 6. out = yg @ W_out.T  (split-K x2, atomic)  M=4096 N=1024 K=2048
    //    256 blocks/z, swizzled: n_blk = XCD exactly (B tile pinned in L2)
    gemm128<2, 1><<<dim3(256, 1, 2), 256, 0, stream>>>(
        yg16, INNER, wout16, INNER, out, nullptr, nullptr,
        DMODEL, DMODEL, INNER / 2, 32);
}

// Round 8
// 386.907 us; speedup vs baseline: 1.1563x; 1.0871x over previous
//
#include <hip/hip_runtime.h>
#include <cstdint>
#include <cstddef>

// Problem constants (fixed by setup_inputs)
#define BB     2
#define LL     2048
#define DMODEL 1024
#define INNER  2048
#define NST    16
#define KCONV  4
#define DRANK  64
#define MROWS  (BB*LL)   // 4096
#define SCH    64        // time chunks
#define TCH    (LL/SCH)  // 32 timesteps per chunk

typedef __attribute__((ext_vector_type(8))) _Float16 half8;   // 8 fp16 = 4 VGPRs
typedef __attribute__((ext_vector_type(4))) _Float16 half4;
typedef __attribute__((ext_vector_type(4))) float floatx4;

// async global->LDS, 16B per lane, dest = wave-uniform base + lane*16
#define GLL(gp, lp) __builtin_amdgcn_global_load_lds( \
    (const __attribute__((address_space(1))) unsigned int*)(gp), \
    (__attribute__((address_space(3))) unsigned int*)(lp), 16, 0, 0)

// ---------------------------------------------------------------------------
// One fused convert kernel: x->x16, W_in->win16, W_out->wout16,
// W_ssm->wssm16 zero-padded from 96 to 128 rows (GLL-safe for GEMM2).
// ---------------------------------------------------------------------------
__global__ __launch_bounds__(256)
void cvt_all(const float* __restrict__ x, const float* __restrict__ w_in,
             const float* __restrict__ w_out, const float* __restrict__ w_ssm,
             _Float16* __restrict__ x16, _Float16* __restrict__ win16,
             _Float16* __restrict__ wout16, _Float16* __restrict__ wssm16)
{
    const int idx = blockIdx.x * 256 + threadIdx.x;
    const int R1 = MROWS * DMODEL / 4;            // x
    const int R2 = R1 + 2 * INNER * DMODEL / 4;   // W_in
    const int R3 = R2 + DMODEL * INNER / 4;       // W_out
    const int R4 = R3 + 128 * INNER / 4;          // W_ssm (padded)
    const float* src; _Float16* dst; int i;
    if (idx < R1)      { src = x;     dst = x16;    i = idx; }
    else if (idx < R2) { src = w_in;  dst = win16;  i = idx - R1; }
    else if (idx < R3) { src = w_out; dst = wout16; i = idx - R2; }
    else if (idx < R4) {
        i = idx - R3;                               // over 128x2048/4
        const int row = i / (INNER / 4);
        half4 h = (half4){0, 0, 0, 0};
        if (row < 96) {
            const float4 v = ((const float4*)w_ssm)[i];
            h.x = (_Float16)v.x; h.y = (_Float16)v.y;
            h.z = (_Float16)v.z; h.w = (_Float16)v.w;
        }
        *(half4*)(wssm16 + (size_t)i * 4) = h;
        return;
    } else return;
    const float4 v = ((const float4*)src)[i];
    half4 h;
    h.x = (_Float16)v.x; h.y = (_Float16)v.y;
    h.z = (_Float16)v.z; h.w = (_Float16)v.w;
    *(half4*)(dst + (size_t)i * 4) = h;
}

// ---------------------------------------------------------------------------
// fp16 MFMA NT-GEMM, 128x128 tile, double-buffered LDS, one barrier/K-iter.
// 4 waves, each 4x4 tiles of mfma_f32_16x16x32_f16, BK=32.
//
// GLL staging: lane L -> row 16g+(L>>2), chunk-slot L&3. The chunk each lane
// FETCHES is XOR-swizzled: c = cs ^ (rt&3) ^ ((rt>>2)&3) so that (a) each
// 4-lane quad covers one row's full 64 B contiguously (TA merges 4 x 16B ->
// 64B L2 requests; the old lane->row map touched 64 lines per GLL — that was
// the request-rate bottleneck), and (b) the b128 fragment reads land 2-way
// uniform on banks (free). Reader chunk offset sw = q ^ (ln15&3) ^
// ((ln15>>2)&3) — lane-constant. LDS layout: [row 0..127][32 k-elems].
//
// EPI 1: cols < INNER -> Cu fp16; cols >= INNER -> Cg fp16 (both ld INNER)
// EPI 2: atomicAdd into fp32 C (ld ldc), guard col < N
// ---------------------------------------------------------------------------
template<int EPI>
__global__ __launch_bounds__(256)
void gemm128(const _Float16* __restrict__ A, int lda,
             const _Float16* __restrict__ B, int ldb,
             float* __restrict__ C, _Float16* __restrict__ Cu,
             _Float16* __restrict__ Cg,
             int ldc, int N, int kchunk)
{
    __shared__ __align__(16) _Float16 sA[2][128 * 32];  // 8 KB each
    __shared__ __align__(16) _Float16 sB[2][128 * 32];

    const int tid  = threadIdx.x;
    const int w    = tid >> 6;        // wave 0..3 (stages rows 32w..32w+31)
    const int lane = tid & 63;
    const int ln15 = lane & 15;
    const int q    = lane >> 4;       // k-quad 0..3
    const int wm   = w & 1, wn = w >> 1;
    const int m0 = blockIdx.x * 128, n0 = blockIdx.y * 128;
    const int kbeg = blockIdx.z * kchunk;

    floatx4 acc[4][4];
    #pragma unroll
    for (int i = 0; i < 4; ++i)
        #pragma unroll
        for (int j = 0; j < 4; ++j)
            acc[i][j] = (floatx4){0.f, 0.f, 0.f, 0.f};

    // --- staging lane mapping (2 GLL-groups per wave per operand)
    const int lr = lane >> 2;         // row within 16-row group
    const int cs = lane & 3;          // fixed LDS chunk slot
    const int g0 = 2 * w, g1 = 2 * w + 1;
    const int rt0 = 16 * g0 + lr, rt1 = 16 * g1 + lr;   // rows in tile
    const int c0 = cs ^ (rt0 & 3) ^ ((rt0 >> 2) & 3);   // fetched chunk
    const int c1 = cs ^ (rt1 & 3) ^ ((rt1 >> 2) & 3);
    const size_t ga0 = (size_t)(m0 + rt0) * lda + kbeg + c0 * 8;
    const size_t ga1 = (size_t)(m0 + rt1) * lda + kbeg + c1 * 8;
    const size_t gb0 = (size_t)(n0 + rt0) * ldb + kbeg + c0 * 8;
    const size_t gb1 = (size_t)(n0 + rt1) * ldb + kbeg + c1 * 8;
    const int lo0 = g0 * 512, lo1 = g1 * 512;           // LDS elem offsets

    // prologue prefetch into buffer 0
    GLL(A + ga0, &sA[0][lo0]);
    GLL(A + ga1, &sA[0][lo1]);
    GLL(B + gb0, &sB[0][lo0]);
    GLL(B + gb1, &sB[0][lo1]);

    // reader swizzle (lane-constant)
    const int sw = q ^ (ln15 & 3) ^ ((ln15 >> 2) & 3);

    const int niter = kchunk >> 5;
    for (int i = 0; i < niter; ++i) {
        __syncthreads();   // drains buf[i&1]'s loads (issued one compute phase ago)
        if (i + 1 < niter) {
            const int kg = (i + 1) * 32;
            const int nb = (i + 1) & 1;
            GLL(A + ga0 + kg, &sA[nb][lo0]);
            GLL(A + ga1 + kg, &sA[nb][lo1]);
            GLL(B + gb0 + kg, &sB[nb][lo0]);
            GLL(B + gb1 + kg, &sB[nb][lo1]);
        }
        const _Float16* bufA = sA[i & 1];
        const _Float16* bufB = sB[i & 1];
        half8 fa[4], fb[4];
        #pragma unroll
        for (int t = 0; t < 4; ++t) {
            fa[t] = *(const half8*)&bufA[(wm * 64 + t * 16 + ln15) * 32 + sw * 8];
            fb[t] = *(const half8*)&bufB[(wn * 64 + t * 16 + ln15) * 32 + sw * 8];
        }
        #pragma unroll
        for (int mt = 0; mt < 4; ++mt)
            #pragma unroll
            for (int nt = 0; nt < 4; ++nt)
                acc[mt][nt] = __builtin_amdgcn_mfma_f32_16x16x32_f16(
                    fa[mt], fb[nt], acc[mt][nt], 0, 0, 0);
    }

    // epilogue: C/D layout col=lane&15, row=q*4+reg
    #pragma unroll
    for (int mt = 0; mt < 4; ++mt) {
        const int rowb = m0 + wm * 64 + mt * 16 + q * 4;
        #pragma unroll
        for (int nt = 0; nt < 4; ++nt) {
            const int col = n0 + wn * 64 + nt * 16 + ln15;
            #pragma unroll
            for (int r = 0; r < 4; ++r) {
                const float v = acc[mt][nt][r];
                const size_t row = (size_t)(rowb + r);
                if (EPI == 1) {
                    if (col < INNER) Cu[row * INNER + col] = (_Float16)v;
                    else Cg[row * INNER + (col - INNER)] = (_Float16)v;
                } else {
                    if (col < N) atomicAdd(&C[row * ldc + col], v);
                }
            }
        }
    }
}

// ---------------------------------------------------------------------------
// fp32 NT-GEMM with softplus(c + bias[col]) epilogue, fp16 output (dt GEMM).
// ---------------------------------------------------------------------------
__global__ __launch_bounds__(256)
void gemm_nt_sp(const float* __restrict__ A, int lda,
                const float* __restrict__ Bm, int ldb,
                _Float16* __restrict__ C, int ldc,
                int K, const float* __restrict__ bias)
{
    __shared__ float As[16][68];
    __shared__ float Bs[16][68];
    const int m0 = blockIdx.x * 64;
    const int n0 = blockIdx.y * 64;
    const int tid = threadIdx.x;
    const int tm = tid >> 4;
    const int tn = tid & 15;
    const int lrow = tid >> 2;
    const int lk   = (tid & 3) << 2;

    float acc[4][4] = {{0.f}};

    for (int k0 = 0; k0 < K; k0 += 16) {
        float4 a4 = *(const float4*)(A + (size_t)(m0 + lrow) * lda + (k0 + lk));
        float4 b4 = *(const float4*)(Bm + (size_t)(n0 + lrow) * ldb + (k0 + lk));
        As[lk+0][lrow] = a4.x; As[lk+1][lrow] = a4.y;
        As[lk+2][lrow] = a4.z; As[lk+3][lrow] = a4.w;
        Bs[lk+0][lrow] = b4.x; Bs[lk+1][lrow] = b4.y;
        Bs[lk+2][lrow] = b4.z; Bs[lk+3][lrow] = b4.w;
        __syncthreads();
        #pragma unroll
        for (int kk = 0; kk < 16; ++kk) {
            float4 av = *(const float4*)&As[kk][tm << 2];
            float4 bv = *(const float4*)&Bs[kk][tn << 2];
            float am[4] = {av.x, av.y, av.z, av.w};
            float bn[4] = {bv.x, bv.y, bv.z, bv.w};
            #pragma unroll
            for (int i = 0; i < 4; ++i)
                #pragma unroll
                for (int j = 0; j < 4; ++j)
                    acc[i][j] = fmaf(am[i], bn[j], acc[i][j]);
        }
        __syncthreads();
    }

    #pragma unroll
    for (int i = 0; i < 4; ++i) {
        const int row = m0 + (tm << 2) + i;
        #pragma unroll
        for (int j = 0; j < 4; ++j) {
            const int col = n0 + (tn << 2) + j;
            float v = acc[i][j] + bias[col];
            v = (v > 20.f) ? v : log1pf(__expf(v));
            C[(size_t)row * ldc + col] = (_Float16)v;
        }
    }
}

// ---------------------------------------------------------------------------
// Depthwise causal conv (k=4) on fp16 u [M, INNER], fp32 math, then SiLU.
// ---------------------------------------------------------------------------
__global__ __launch_bounds__(256)
void conv_silu(const _Float16* __restrict__ u_in,
               const float* __restrict__ conv_w,
               _Float16* __restrict__ uc16)
{
    const int idx = blockIdx.x * 256 + threadIdx.x;  // over M*INNER/4
    const int c4 = idx & (INNER / 4 - 1);
    const int t  = (idx >> 9) & (LL - 1);
    const int bb = idx >> 20;
    const int d0 = c4 * 4;
    const size_t base = (size_t)bb * LL;

    const float4 w0 = *(const float4*)(conv_w + (d0 + 0) * KCONV);
    const float4 w1 = *(const float4*)(conv_w + (d0 + 1) * KCONV);
    const float4 w2 = *(const float4*)(conv_w + (d0 + 2) * KCONV);
    const float4 w3 = *(const float4*)(conv_w + (d0 + 3) * KCONV);
    const float wj[4][4] = {{w0.x,w0.y,w0.z,w0.w}, {w1.x,w1.y,w1.z,w1.w},
                            {w2.x,w2.y,w2.z,w2.w}, {w3.x,w3.y,w3.z,w3.w}};
    float s[4] = {0.f, 0.f, 0.f, 0.f};
    #pragma unroll
    for (int j = 0; j < KCONV; ++j) {
        const int ts = t + j - (KCONV - 1);
        if (ts >= 0) {
            const half4 v = *(const half4*)(u_in + (base + ts) * INNER + d0);
            s[0] = fmaf((float)v.x, wj[0][j], s[0]);
            s[1] = fmaf((float)v.y, wj[1][j], s[1]);
            s[2] = fmaf((float)v.z, wj[2][j], s[2]);
            s[3] = fmaf((float)v.w, wj[3][j], s[3]);
        }
    }
    half4 o16;
    o16.x = (_Float16)(s[0] / (1.f + __expf(-s[0])));
    o16.y = (_Float16)(s[1] / (1.f + __expf(-s[1])));
    o16.z = (_Float16)(s[2] / (1.f + __expf(-s[2])));
    o16.w = (_Float16)(s[3] / (1.f + __expf(-s[3])));
    *(half4*)(uc16 + (base + t) * INNER + d0) = o16;
}

// ---------------------------------------------------------------------------
// Scan pass 1: per-chunk summaries (h[16] in registers per thread-channel).
// ---------------------------------------------------------------------------
__global__ __launch_bounds__(256)
void scan_pass1(const _Float16* __restrict__ uc16,
                const _Float16* __restrict__ dt16,
                const float* __restrict__ params,
                const float* __restrict__ log_A,
                float* __restrict__ Hout,
                float* __restrict__ sumdt_out)
{
    const int bid = blockIdx.x;
    const int c   = bid & (SCH - 1);
    const int cg  = (bid >> 6) & 7;
    const int b   = bid >> 9;
    const int tid = threadIdx.x;
    const int d   = cg * 256 + tid;
    const size_t rowbase = (size_t)b * LL + (size_t)c * TCH;

    float A[NST];
    #pragma unroll
    for (int n = 0; n < NST; n += 4) {
        float4 v = *(const float4*)(log_A + (size_t)d * NST + n);
        A[n+0] = -__expf(v.x); A[n+1] = -__expf(v.y);
        A[n+2] = -__expf(v.z); A[n+3] = -__expf(v.w);
    }

    __shared__ float Bs[TCH * NST];
    for (int i = tid; i < TCH * NST; i += 256) {
        const int t = i >> 4, j = i & 15;
        Bs[i] = params[(rowbase + t) * 96 + DRANK + j];
    }
    __syncthreads();

    float h[NST];
    #pragma unroll
    for (int n = 0; n < NST; ++n) h[n] = 0.f;
    float sdt = 0.f;

    #pragma unroll 4
    for (int t = 0; t < TCH; ++t) {
        const float dtv = (float)dt16[(rowbase + t) * INNER + d];
        const float uv  = (float)uc16[(rowbase + t) * INNER + d];
        const float du = dtv * uv;
        sdt += dtv;
        const float4* Bp = (const float4*)&Bs[t * NST];
        const float4 B0 = Bp[0], B1 = Bp[1], B2 = Bp[2], B3 = Bp[3];
        const float Bv[NST] = {B0.x,B0.y,B0.z,B0.w, B1.x,B1.y,B1.z,B1.w,
                               B2.x,B2.y,B2.z,B2.w, B3.x,B3.y,B3.z,B3.w};
        #pragma unroll
        for (int n = 0; n < NST; ++n)
            h[n] = fmaf(__expf(dtv * A[n]), h[n], du * Bv[n]);
    }

    const size_t o = ((size_t)(b * SCH + c) * INNER + d) * NST;
    #pragma unroll
    for (int n = 0; n < NST; n += 4)
        *(float4*)(Hout + o + n) = make_float4(h[n], h[n+1], h[n+2], h[n+3]);
    sumdt_out[(size_t)(b * SCH + c) * INNER + d] = sdt;
}

// ---------------------------------------------------------------------------
// Scan pass 2: serial combine over chunks. One thread = one (b,d,n).
// ---------------------------------------------------------------------------
__global__ __launch_bounds__(256)
void scan_pass2(const float* __restrict__ Hbuf,
                const float* __restrict__ sumdt,
                const float* __restrict__ log_A,
                float* __restrict__ hinit)
{
    const int idx = blockIdx.x * 256 + threadIdx.x;
    const int n = idx & 15;
    const int d = (idx >> 4) & (INNER - 1);
    const int b = idx >> 15;
    const float An = -__expf(log_A[(size_t)d * NST + n]);
    float h = 0.f;
    for (int c = 0; c < SCH; ++c) {
        const size_t o = ((size_t)(b * SCH + c) * INNER + d) * NST + n;
        hinit[o] = h;
        const float P = __expf(An * sumdt[(size_t)(b * SCH + c) * INNER + d]);
        h = Hbuf[o] + P * h;
    }
}

// ---------------------------------------------------------------------------
// Scan pass 3: re-scan each chunk from h_init, fused epilogue:
// yg = (y + u*D) * silu(gate) -> fp16 (feeds GEMM3).
// ---------------------------------------------------------------------------
__global__ __launch_bounds__(256)
void scan_pass3(const _Float16* __restrict__ uc16,
                const _Float16* __restrict__ dt16,
                const float* __restrict__ params,
                const _Float16* __restrict__ gate16,  // [M, INNER]
                const float* __restrict__ log_A,
                const float* __restrict__ Dv,
                const float* __restrict__ hinit,
                _Float16* __restrict__ yg16)          // [M, INNER]
{
    const int bid = blockIdx.x;
    const int c   = bid & (SCH - 1);
    const int cg  = (bid >> 6) & 7;
    const int b   = bid >> 9;
    const int tid = threadIdx.x;
    const int d   = cg * 256 + tid;
    const size_t rowbase = (size_t)b * LL + (size_t)c * TCH;

    float A[NST];
    #pragma unroll
    for (int n = 0; n < NST; n += 4) {
        float4 v = *(const float4*)(log_A + (size_t)d * NST + n);
        A[n+0] = -__expf(v.x); A[n+1] = -__expf(v.y);
        A[n+2] = -__expf(v.z); A[n+3] = -__expf(v.w);
    }
    const float Dd = Dv[d];

    __shared__ float BCs[TCH * 32];
    for (int i = tid; i < TCH * 32; i += 256) {
        const int t = i >> 5, j = i & 31;
        BCs[i] = params[(rowbase + t) * 96 + DRANK + j];
    }

    float h[NST];
    {
        const size_t o = ((size_t)(b * SCH + c) * INNER + d) * NST;
        #pragma unroll
        for (int n = 0; n < NST; n += 4) {
            float4 v = *(const float4*)(hinit + o + n);
            h[n] = v.x; h[n+1] = v.y; h[n+2] = v.z; h[n+3] = v.w;
        }
    }
    __syncthreads();

    #pragma unroll 2
    for (int t = 0; t < TCH; ++t) {
        const float dtv = (float)dt16[(rowbase + t) * INNER + d];
        const float uv  = (float)uc16[(rowbase + t) * INNER + d];
        const float gv  = (float)gate16[(rowbase + t) * INNER + d];
        const float du = dtv * uv;
        const float4* Bp = (const float4*)&BCs[t * 32];
        const float4 B0 = Bp[0], B1 = Bp[1], B2 = Bp[2], B3 = Bp[3];
        const float4 C0 = Bp[4], C1 = Bp[5], C2 = Bp[6], C3 = Bp[7];
        const float Bv[NST] = {B0.x,B0.y,B0.z,B0.w, B1.x,B1.y,B1.z,B1.w,
                               B2.x,B2.y,B2.z,B2.w, B3.x,B3.y,B3.z,B3.w};
        const float Cv[NST] = {C0.x,C0.y,C0.z,C0.w, C1.x,C1.y,C1.z,C1.w,
                               C2.x,C2.y,C2.z,C2.w, C3.x,C3.y,C3.z,C3.w};
        #pragma unroll
        for (int n = 0; n < NST; ++n)
            h[n] = fmaf(__expf(dtv * A[n]), h[n], du * Bv[n]);
        float p[8];
        #pragma unroll
        for (int n = 0; n < 8; ++n)
            p[n] = fmaf(h[n], Cv[n], h[n+8] * Cv[n+8]);
        const float y = ((p[0]+p[1]) + (p[2]+p[3])) + ((p[4]+p[5]) + (p[6]+p[7]));
        const float sg = gv / (1.f + __expf(-gv));
        yg16[(rowbase + t) * INNER + d] = (_Float16)((y + uv * Dd) * sg);
    }
}

// ---------------------------------------------------------------------------
extern "C" void kernel_launch(void* const* d_in, const int* in_sizes, int n_in,
                              void* d_out, int out_size, void* d_ws, size_t ws_size,
                              hipStream_t stream)
{
    const float* x     = (const float*)d_in[0];
    const float* W_in  = (const float*)d_in[1];
    const float* convw = (const float*)d_in[2];
    const float* W_ssm = (const float*)d_in[3];
    const float* W_dt  = (const float*)d_in[4];
    const float* b_dt  = (const float*)d_in[5];
    const float* log_A = (const float*)d_in[6];
    const float* Dv    = (const float*)d_in[7];
    const float* W_out = (const float*)d_in[8];
    float* out = (float*)d_out;

    float* ws = (float*)d_ws;
    float* params = ws;                                       // 393216
    float* Hbuf   = params + (size_t)MROWS * 96;              // 4.2M
    float* hinit  = Hbuf   + (size_t)BB * SCH * INNER * NST;  // 4.2M
    float* sumdt  = hinit  + (size_t)BB * SCH * INNER * NST;  // 262144
    _Float16* x16    = (_Float16*)(sumdt + (size_t)BB * SCH * INNER);
    _Float16* win16  = x16    + (size_t)MROWS * DMODEL;
    _Float16* wout16 = win16  + (size_t)(2 * INNER) * DMODEL;
    _Float16* wssm16 = wout16 + (size_t)DMODEL * INNER;       // 128 x 2048 (padded)
    _Float16* u16raw = wssm16 + (size_t)128 * INNER;          // GEMM1 u-half
    _Float16* gate16 = u16raw + (size_t)MROWS * INNER;
    _Float16* uc16   = gate16 + (size_t)MROWS * INNER;        // conv+silu output
    _Float16* dt16   = uc16   + (size_t)MROWS * INNER;
    _Float16* yg16   = dt16   + (size_t)MROWS * INNER;

    // zero accumulators for split-K atomics
    hipMemsetAsync(params, 0, (size_t)MROWS * 96 * sizeof(float), stream);
    hipMemsetAsync(out, 0, (size_t)MROWS * DMODEL * sizeof(float), stream);

    // 0. all fp32->fp16 converts (+ W_ssm zero-pad to 128 rows)
    {
        const int total4 = MROWS * DMODEL / 4 + 2 * INNER * DMODEL / 4 +
                           DMODEL * INNER / 4 + 128 * INNER / 4;
        cvt_all<<<(total4 + 255) / 256, 256, 0, stream>>>(
            x, W_in, W_out, W_ssm, x16, win16, wout16, wssm16);
    }

    // 1. xz = x @ W_in.T -> u16raw | gate16   M=4096 N=4096 K=1024
    gemm128<1><<<dim3(32, 32, 1), 256, 0, stream>>>(
        x16, DMODEL, win16, DMODEL, nullptr, u16raw, gate16,
        0, 2 * INNER, DMODEL);

    // 2. uc16 = silu(causal_conv(u16raw))
    conv_silu<<<(MROWS * INNER / 4) / 256, 256, 0, stream>>>(
        u16raw, convw, uc16);

    // 3. params = uc16 @ wssm16.T  (split-K x8, atomic)  N=96 (tile covers 128)
    gemm128<2><<<dim3(32, 1, 8), 256, 0, stream>>>(
        uc16, INNER, wssm16, INNER, params, nullptr, nullptr,
        96, 96, INNER / 8);

    // 4. dt16 = softplus(d_low @ W_dt.T + b_dt)  M=4096 N=2048 K=64 (lda=96)
    gemm_nt_sp<<<dim3(64, 32), 256, 0, stream>>>(
        params, 96, W_dt, DRANK, dt16, INNER, DRANK, b_dt);

    // 5. chunked selective scan (3 passes); pass3 emits fp16 yg
    scan_pass1<<<BB * (INNER / 256) * SCH, 256, 0, stream>>>(
        uc16, dt16, params, log_A, Hbuf, sumdt);
    scan_pass2<<<BB * INNER * NST / 256, 256, 0, stream>>>(
        Hbuf, sumdt, log_A, hinit);
    scan_pass3<<<BB * (INNER / 256) * SCH, 256, 0, stream>>>(
        uc16, dt16, params, gate16, log_A, Dv, hinit, yg16);

    // 6. out = yg @ W_out.T  (split-K x2, atomic)  M=4096 N=1024 K=2048
    gemm128<2><<<dim3(32, 8, 2), 256, 0, stream>>>(
        yg16, INNER, wout16, INNER, out, nullptr, nullptr,
        DMODEL, DMODEL, INNER / 2);
}

// Round 9
// 362.316 us; speedup vs baseline: 1.2348x; 1.0679x over previous
//
#include <hip/hip_runtime.h>
#include <cstdint>
#include <cstddef>

// Problem constants (fixed by setup_inputs)
#define BB     2
#define LL     2048
#define DMODEL 1024
#define INNER  2048
#define NST    16
#define KCONV  4
#define DRANK  64
#define MROWS  (BB*LL)   // 4096
#define SCH    64        // time chunks
#define TCH    (LL/SCH)  // 32 timesteps per chunk

typedef __attribute__((ext_vector_type(8))) _Float16 half8;   // 8 fp16 = 4 VGPRs
typedef __attribute__((ext_vector_type(4))) _Float16 half4;
typedef __attribute__((ext_vector_type(4))) float floatx4;

// async global->LDS, 16B per lane, dest = wave-uniform base + lane*16
#define GLL(gp, lp) __builtin_amdgcn_global_load_lds( \
    (const __attribute__((address_space(1))) unsigned int*)(gp), \
    (__attribute__((address_space(3))) unsigned int*)(lp), 16, 0, 0)

// ---------------------------------------------------------------------------
// One fused convert kernel: x->x16, W_in->win16, W_out->wout16,
// W_ssm->wssm16 zero-padded from 96 to 128 rows (GLL-safe for GEMM2).
// ---------------------------------------------------------------------------
__global__ __launch_bounds__(256)
void cvt_all(const float* __restrict__ x, const float* __restrict__ w_in,
             const float* __restrict__ w_out, const float* __restrict__ w_ssm,
             _Float16* __restrict__ x16, _Float16* __restrict__ win16,
             _Float16* __restrict__ wout16, _Float16* __restrict__ wssm16)
{
    const int idx = blockIdx.x * 256 + threadIdx.x;
    const int R1 = MROWS * DMODEL / 4;            // x
    const int R2 = R1 + 2 * INNER * DMODEL / 4;   // W_in
    const int R3 = R2 + DMODEL * INNER / 4;       // W_out
    const int R4 = R3 + 128 * INNER / 4;          // W_ssm (padded)
    const float* src; _Float16* dst; int i;
    if (idx < R1)      { src = x;     dst = x16;    i = idx; }
    else if (idx < R2) { src = w_in;  dst = win16;  i = idx - R1; }
    else if (idx < R3) { src = w_out; dst = wout16; i = idx - R2; }
    else if (idx < R4) {
        i = idx - R3;                               // over 128x2048/4
        const int row = i / (INNER / 4);
        half4 h = (half4){0, 0, 0, 0};
        if (row < 96) {
            const float4 v = ((const float4*)w_ssm)[i];
            h.x = (_Float16)v.x; h.y = (_Float16)v.y;
            h.z = (_Float16)v.z; h.w = (_Float16)v.w;
        }
        *(half4*)(wssm16 + (size_t)i * 4) = h;
        return;
    } else return;
    const float4 v = ((const float4*)src)[i];
    half4 h;
    h.x = (_Float16)v.x; h.y = (_Float16)v.y;
    h.z = (_Float16)v.z; h.w = (_Float16)v.w;
    *(half4*)(dst + (size_t)i * 4) = h;
}

// ---------------------------------------------------------------------------
// fp16 MFMA NT-GEMM, 128x128 tile, double-buffered LDS, one barrier/K-iter,
// coalesced GLL staging with XOR chunk swizzle (see r8).
//
// NN8 > 0: XCD-aware 2D block mapping. xcd = blockIdx.x & 7 (HW round-robin);
// XCD k owns n_blk ≡ k (mod 8), NN8 n-columns; within an XCD the order is
// [m-octet][n_sub][m_in] so the resident working set is 8 A-tiles + NN8
// B-tiles (~3 MB) — stays in the XCD's 4 MB L2.
// NN8 == 0: plain 2D grid (blockIdx.x = m, blockIdx.y = n).
//
// EPI 1: cols < INNER -> Cu fp16; cols >= INNER -> Cg fp16 (both ld INNER)
// EPI 0: plain fp32 store C[row*ldc+col], C += blockIdx.z * zstride
// ---------------------------------------------------------------------------
template<int EPI, int NN8>
__global__ __launch_bounds__(256)
void gemm128(const _Float16* __restrict__ A, int lda,
             const _Float16* __restrict__ B, int ldb,
             float* __restrict__ C, _Float16* __restrict__ Cu,
             _Float16* __restrict__ Cg,
             int ldc, int kchunk, size_t zstride)
{
    __shared__ __align__(16) _Float16 sA[2][128 * 32];  // 8 KB each
    __shared__ __align__(16) _Float16 sB[2][128 * 32];

    int m_blk, n_blk;
    if (NN8 > 0) {
        const int xcd = blockIdx.x & 7;
        const int t   = blockIdx.x >> 3;
        const int m_in  = t & 7;
        const int rest  = t >> 3;
        const int n_sub = rest % NN8;
        const int oct   = rest / NN8;
        m_blk = oct * 8 + m_in;
        n_blk = xcd + 8 * n_sub;
    } else {
        m_blk = blockIdx.x;
        n_blk = blockIdx.y;
    }

    const int tid  = threadIdx.x;
    const int w    = tid >> 6;        // wave 0..3 (stages rows 32w..32w+31)
    const int lane = tid & 63;
    const int ln15 = lane & 15;
    const int q    = lane >> 4;       // k-quad 0..3
    const int wm   = w & 1, wn = w >> 1;
    const int m0 = m_blk * 128, n0 = n_blk * 128;
    const int kbeg = blockIdx.z * kchunk;
    if (EPI == 0) C += (size_t)blockIdx.z * zstride;

    floatx4 acc[4][4];
    #pragma unroll
    for (int i = 0; i < 4; ++i)
        #pragma unroll
        for (int j = 0; j < 4; ++j)
            acc[i][j] = (floatx4){0.f, 0.f, 0.f, 0.f};

    // --- staging lane mapping (2 GLL-groups per wave per operand)
    const int lr = lane >> 2;         // row within 16-row group
    const int cs = lane & 3;          // fixed LDS chunk slot
    const int g0 = 2 * w, g1 = 2 * w + 1;
    const int rt0 = 16 * g0 + lr, rt1 = 16 * g1 + lr;   // rows in tile
    const int c0 = cs ^ (rt0 & 3) ^ ((rt0 >> 2) & 3);   // fetched chunk
    const int c1 = cs ^ (rt1 & 3) ^ ((rt1 >> 2) & 3);
    const size_t ga0 = (size_t)(m0 + rt0) * lda + kbeg + c0 * 8;
    const size_t ga1 = (size_t)(m0 + rt1) * lda + kbeg + c1 * 8;
    const size_t gb0 = (size_t)(n0 + rt0) * ldb + kbeg + c0 * 8;
    const size_t gb1 = (size_t)(n0 + rt1) * ldb + kbeg + c1 * 8;
    const int lo0 = g0 * 512, lo1 = g1 * 512;           // LDS elem offsets

    // prologue prefetch into buffer 0
    GLL(A + ga0, &sA[0][lo0]);
    GLL(A + ga1, &sA[0][lo1]);
    GLL(B + gb0, &sB[0][lo0]);
    GLL(B + gb1, &sB[0][lo1]);

    // reader swizzle (lane-constant)
    const int sw = q ^ (ln15 & 3) ^ ((ln15 >> 2) & 3);

    const int niter = kchunk >> 5;
    for (int i = 0; i < niter; ++i) {
        __syncthreads();   // drains buf[i&1]'s loads (issued one compute phase ago)
        if (i + 1 < niter) {
            const int kg = (i + 1) * 32;
            const int nb = (i + 1) & 1;
            GLL(A + ga0 + kg, &sA[nb][lo0]);
            GLL(A + ga1 + kg, &sA[nb][lo1]);
            GLL(B + gb0 + kg, &sB[nb][lo0]);
            GLL(B + gb1 + kg, &sB[nb][lo1]);
        }
        const _Float16* bufA = sA[i & 1];
        const _Float16* bufB = sB[i & 1];
        half8 fa[4], fb[4];
        #pragma unroll
        for (int t = 0; t < 4; ++t) {
            fa[t] = *(const half8*)&bufA[(wm * 64 + t * 16 + ln15) * 32 + sw * 8];
            fb[t] = *(const half8*)&bufB[(wn * 64 + t * 16 + ln15) * 32 + sw * 8];
        }
        #pragma unroll
        for (int mt = 0; mt < 4; ++mt)
            #pragma unroll
            for (int nt = 0; nt < 4; ++nt)
                acc[mt][nt] = __builtin_amdgcn_mfma_f32_16x16x32_f16(
                    fa[mt], fb[nt], acc[mt][nt], 0, 0, 0);
    }

    // epilogue: C/D layout col=lane&15, row=q*4+reg
    #pragma unroll
    for (int mt = 0; mt < 4; ++mt) {
        const int rowb = m0 + wm * 64 + mt * 16 + q * 4;
        #pragma unroll
        for (int nt = 0; nt < 4; ++nt) {
            const int col = n0 + wn * 64 + nt * 16 + ln15;
            #pragma unroll
            for (int r = 0; r < 4; ++r) {
                const float v = acc[mt][nt][r];
                const size_t row = (size_t)(rowb + r);
                if (EPI == 1) {
                    if (col < INNER) Cu[row * INNER + col] = (_Float16)v;
                    else Cg[row * INNER + (col - INNER)] = (_Float16)v;
                } else {
                    C[row * ldc + col] = v;
                }
            }
        }
    }
}

// ---------------------------------------------------------------------------
// Reduce GEMM2's 8 split-K partials [8][MROWS][128] -> params [MROWS][96]
// ---------------------------------------------------------------------------
__global__ __launch_bounds__(256)
void reduce_params(const float* __restrict__ part, float* __restrict__ params)
{
    const int idx = blockIdx.x * 256 + threadIdx.x;   // over MROWS*24
    if (idx >= MROWS * 24) return;
    const int r = idx / 24;
    const int c = (idx - r * 24) * 4;
    float4 s = make_float4(0.f, 0.f, 0.f, 0.f);
    #pragma unroll
    for (int z = 0; z < 8; ++z) {
        const float4 v = *(const float4*)(part + ((size_t)z * MROWS + r) * 128 + c);
        s.x += v.x; s.y += v.y; s.z += v.z; s.w += v.w;
    }
    *(float4*)(params + (size_t)r * 96 + c) = s;
}

// ---------------------------------------------------------------------------
// fp32 NT-GEMM with softplus(c + bias[col]) epilogue, fp16 output (dt GEMM).
// ---------------------------------------------------------------------------
__global__ __launch_bounds__(256)
void gemm_nt_sp(const float* __restrict__ A, int lda,
                const float* __restrict__ Bm, int ldb,
                _Float16* __restrict__ C, int ldc,
                int K, const float* __restrict__ bias)
{
    __shared__ float As[16][68];
    __shared__ float Bs[16][68];
    const int m0 = blockIdx.x * 64;
    const int n0 = blockIdx.y * 64;
    const int tid = threadIdx.x;
    const int tm = tid >> 4;
    const int tn = tid & 15;
    const int lrow = tid >> 2;
    const int lk   = (tid & 3) << 2;

    float acc[4][4] = {{0.f}};

    for (int k0 = 0; k0 < K; k0 += 16) {
        float4 a4 = *(const float4*)(A + (size_t)(m0 + lrow) * lda + (k0 + lk));
        float4 b4 = *(const float4*)(Bm + (size_t)(n0 + lrow) * ldb + (k0 + lk));
        As[lk+0][lrow] = a4.x; As[lk+1][lrow] = a4.y;
        As[lk+2][lrow] = a4.z; As[lk+3][lrow] = a4.w;
        Bs[lk+0][lrow] = b4.x; Bs[lk+1][lrow] = b4.y;
        Bs[lk+2][lrow] = b4.z; Bs[lk+3][lrow] = b4.w;
        __syncthreads();
        #pragma unroll
        for (int kk = 0; kk < 16; ++kk) {
            float4 av = *(const float4*)&As[kk][tm << 2];
            float4 bv = *(const float4*)&Bs[kk][tn << 2];
            float am[4] = {av.x, av.y, av.z, av.w};
            float bn[4] = {bv.x, bv.y, bv.z, bv.w};
            #pragma unroll
            for (int i = 0; i < 4; ++i)
                #pragma unroll
                for (int j = 0; j < 4; ++j)
                    acc[i][j] = fmaf(am[i], bn[j], acc[i][j]);
        }
        __syncthreads();
    }

    #pragma unroll
    for (int i = 0; i < 4; ++i) {
        const int row = m0 + (tm << 2) + i;
        #pragma unroll
        for (int j = 0; j < 4; ++j) {
            const int col = n0 + (tn << 2) + j;
            float v = acc[i][j] + bias[col];
            v = (v > 20.f) ? v : log1pf(__expf(v));
            C[(size_t)row * ldc + col] = (_Float16)v;
        }
    }
}

// ---------------------------------------------------------------------------
// Depthwise causal conv (k=4) on fp16 u [M, INNER], fp32 math, then SiLU.
// ---------------------------------------------------------------------------
__global__ __launch_bounds__(256)
void conv_silu(const _Float16* __restrict__ u_in,
               const float* __restrict__ conv_w,
               _Float16* __restrict__ uc16)
{
    const int idx = blockIdx.x * 256 + threadIdx.x;  // over M*INNER/4
    const int c4 = idx & (INNER / 4 - 1);
    const int t  = (idx >> 9) & (LL - 1);
    const int bb = idx >> 20;
    const int d0 = c4 * 4;
    const size_t base = (size_t)bb * LL;

    const float4 w0 = *(const float4*)(conv_w + (d0 + 0) * KCONV);
    const float4 w1 = *(const float4*)(conv_w + (d0 + 1) * KCONV);
    const float4 w2 = *(const float4*)(conv_w + (d0 + 2) * KCONV);
    const float4 w3 = *(const float4*)(conv_w + (d0 + 3) * KCONV);
    const float wj[4][4] = {{w0.x,w0.y,w0.z,w0.w}, {w1.x,w1.y,w1.z,w1.w},
                            {w2.x,w2.y,w2.z,w2.w}, {w3.x,w3.y,w3.z,w3.w}};
    float s[4] = {0.f, 0.f, 0.f, 0.f};
    #pragma unroll
    for (int j = 0; j < KCONV; ++j) {
        const int ts = t + j - (KCONV - 1);
        if (ts >= 0) {
            const half4 v = *(const half4*)(u_in + (base + ts) * INNER + d0);
            s[0] = fmaf((float)v.x, wj[0][j], s[0]);
            s[1] = fmaf((float)v.y, wj[1][j], s[1]);
            s[2] = fmaf((float)v.z, wj[2][j], s[2]);
            s[3] = fmaf((float)v.w, wj[3][j], s[3]);
        }
    }
    half4 o16;
    o16.x = (_Float16)(s[0] / (1.f + __expf(-s[0])));
    o16.y = (_Float16)(s[1] / (1.f + __expf(-s[1])));
    o16.z = (_Float16)(s[2] / (1.f + __expf(-s[2])));
    o16.w = (_Float16)(s[3] / (1.f + __expf(-s[3])));
    *(half4*)(uc16 + (base + t) * INNER + d0) = o16;
}

// ---------------------------------------------------------------------------
// Scan pass 1: per-chunk summaries (h[16] in registers per thread-channel).
// ---------------------------------------------------------------------------
__global__ __launch_bounds__(256)
void scan_pass1(const _Float16* __restrict__ uc16,
                const _Float16* __restrict__ dt16,
                const float* __restrict__ params,
                const float* __restrict__ log_A,
                float* __restrict__ Hout,
                float* __restrict__ sumdt_out)
{
    const int bid = blockIdx.x;
    const int c   = bid & (SCH - 1);
    const int cg  = (bid >> 6) & 7;
    const int b   = bid >> 9;
    const int tid = threadIdx.x;
    const int d   = cg * 256 + tid;
    const size_t rowbase = (size_t)b * LL + (size_t)c * TCH;

    float A[NST];
    #pragma unroll
    for (int n = 0; n < NST; n += 4) {
        float4 v = *(const float4*)(log_A + (size_t)d * NST + n);
        A[n+0] = -__expf(v.x); A[n+1] = -__expf(v.y);
        A[n+2] = -__expf(v.z); A[n+3] = -__expf(v.w);
    }

    __shared__ float Bs[TCH * NST];
    for (int i = tid; i < TCH * NST; i += 256) {
        const int t = i >> 4, j = i & 15;
        Bs[i] = params[(rowbase + t) * 96 + DRANK + j];
    }
    __syncthreads();

    float h[NST];
    #pragma unroll
    for (int n = 0; n < NST; ++n) h[n] = 0.f;
    float sdt = 0.f;

    #pragma unroll 4
    for (int t = 0; t < TCH; ++t) {
        const float dtv = (float)dt16[(rowbase + t) * INNER + d];
        const float uv  = (float)uc16[(rowbase + t) * INNER + d];
        const float du = dtv * uv;
        sdt += dtv;
        const float4* Bp = (const float4*)&Bs[t * NST];
        const float4 B0 = Bp[0], B1 = Bp[1], B2 = Bp[2], B3 = Bp[3];
        const float Bv[NST] = {B0.x,B0.y,B0.z,B0.w, B1.x,B1.y,B1.z,B1.w,
                               B2.x,B2.y,B2.z,B2.w, B3.x,B3.y,B3.z,B3.w};
        #pragma unroll
        for (int n = 0; n < NST; ++n)
            h[n] = fmaf(__expf(dtv * A[n]), h[n], du * Bv[n]);
    }

    const size_t o = ((size_t)(b * SCH + c) * INNER + d) * NST;
    #pragma unroll
    for (int n = 0; n < NST; n += 4)
        *(float4*)(Hout + o + n) = make_float4(h[n], h[n+1], h[n+2], h[n+3]);
    sumdt_out[(size_t)(b * SCH + c) * INNER + d] = sdt;
}

// ---------------------------------------------------------------------------
// Scan pass 2: serial combine over chunks. One thread = one (b,d,n).
// ---------------------------------------------------------------------------
__global__ __launch_bounds__(256)
void scan_pass2(const float* __restrict__ Hbuf,
                const float* __restrict__ sumdt,
                const float* __restrict__ log_A,
                float* __restrict__ hinit)
{
    const int idx = blockIdx.x * 256 + threadIdx.x;
    const int n = idx & 15;
    const int d = (idx >> 4) & (INNER - 1);
    const int b = idx >> 15;
    const float An = -__expf(log_A[(size_t)d * NST + n]);
    float h = 0.f;
    for (int c = 0; c < SCH; ++c) {
        const size_t o = ((size_t)(b * SCH + c) * INNER + d) * NST + n;
        hinit[o] = h;
        const float P = __expf(An * sumdt[(size_t)(b * SCH + c) * INNER + d]);
        h = Hbuf[o] + P * h;
    }
}

// ---------------------------------------------------------------------------
// Scan pass 3: re-scan each chunk from h_init, fused epilogue:
// yg = (y + u*D) * silu(gate) -> fp16 (feeds GEMM3).
// ---------------------------------------------------------------------------
__global__ __launch_bounds__(256)
void scan_pass3(const _Float16* __restrict__ uc16,
                const _Float16* __restrict__ dt16,
                const float* __restrict__ params,
                const _Float16* __restrict__ gate16,  // [M, INNER]
                const float* __restrict__ log_A,
                const float* __restrict__ Dv,
                const float* __restrict__ hinit,
                _Float16* __restrict__ yg16)          // [M, INNER]
{
    const int bid = blockIdx.x;
    const int c   = bid & (SCH - 1);
    const int cg  = (bid >> 6) & 7;
    const int b   = bid >> 9;
    const int tid = threadIdx.x;
    const int d   = cg * 256 + tid;
    const size_t rowbase = (size_t)b * LL + (size_t)c * TCH;

    float A[NST];
    #pragma unroll
    for (int n = 0; n < NST; n += 4) {
        float4 v = *(const float4*)(log_A + (size_t)d * NST + n);
        A[n+0] = -__expf(v.x); A[n+1] = -__expf(v.y);
        A[n+2] = -__expf(v.z); A[n+3] = -__expf(v.w);
    }
    const float Dd = Dv[d];

    __shared__ float BCs[TCH * 32];
    for (int i = tid; i < TCH * 32; i += 256) {
        const int t = i >> 5, j = i & 31;
        BCs[i] = params[(rowbase + t) * 96 + DRANK + j];
    }

    float h[NST];
    {
        const size_t o = ((size_t)(b * SCH + c) * INNER + d) * NST;
        #pragma unroll
        for (int n = 0; n < NST; n += 4) {
            float4 v = *(const float4*)(hinit + o + n);
            h[n] = v.x; h[n+1] = v.y; h[n+2] = v.z; h[n+3] = v.w;
        }
    }
    __syncthreads();

    #pragma unroll 2
    for (int t = 0; t < TCH; ++t) {
        const float dtv = (float)dt16[(rowbase + t) * INNER + d];
        const float uv  = (float)uc16[(rowbase + t) * INNER + d];
        const float gv  = (float)gate16[(rowbase + t) * INNER + d];
        const float du = dtv * uv;
        const float4* Bp = (const float4*)&BCs[t * 32];
        const float4 B0 = Bp[0], B1 = Bp[1], B2 = Bp[2], B3 = Bp[3];
        const float4 C0 = Bp[4], C1 = Bp[5], C2 = Bp[6], C3 = Bp[7];
        const float Bv[NST] = {B0.x,B0.y,B0.z,B0.w, B1.x,B1.y,B1.z,B1.w,
                               B2.x,B2.y,B2.z,B2.w, B3.x,B3.y,B3.z,B3.w};
        const float Cv[NST] = {C0.x,C0.y,C0.z,C0.w, C1.x,C1.y,C1.z,C1.w,
                               C2.x,C2.y,C2.z,C2.w, C3.x,C3.y,C3.z,C3.w};
        #pragma unroll
        for (int n = 0; n < NST; ++n)
            h[n] = fmaf(__expf(dtv * A[n]), h[n], du * Bv[n]);
        float p[8];
        #pragma unroll
        for (int n = 0; n < 8; ++n)
            p[n] = fmaf(h[n], Cv[n], h[n+8] * Cv[n+8]);
        const float y = ((p[0]+p[1]) + (p[2]+p[3])) + ((p[4]+p[5]) + (p[6]+p[7]));
        const float sg = gv / (1.f + __expf(-gv));
        yg16[(rowbase + t) * INNER + d] = (_Float16)((y + uv * Dd) * sg);
    }
}

// ---------------------------------------------------------------------------
extern "C" void kernel_launch(void* const* d_in, const int* in_sizes, int n_in,
                              void* d_out, int out_size, void* d_ws, size_t ws_size,
                              hipStream_t stream)
{
    const float* x     = (const float*)d_in[0];
    const float* W_in  = (const float*)d_in[1];
    const float* convw = (const float*)d_in[2];
    const float* W_ssm = (const float*)d_in[3];
    const float* W_dt  = (const float*)d_in[4];
    const float* b_dt  = (const float*)d_in[5];
    const float* log_A = (const float*)d_in[6];
    const float* Dv    = (const float*)d_in[7];
    const float* W_out = (const float*)d_in[8];
    float* out = (float*)d_out;

    float* ws = (float*)d_ws;
    float* params = ws;                                       // 4096*96
    float* ppart  = params + (size_t)MROWS * 96;              // 8*4096*128
    float* Hbuf   = ppart  + (size_t)8 * MROWS * 128;         // 4.2M
    float* hinit  = Hbuf   + (size_t)BB * SCH * INNER * NST;  // 4.2M
    float* sumdt  = hinit  + (size_t)BB * SCH * INNER * NST;  // 262144
    _Float16* x16    = (_Float16*)(sumdt + (size_t)BB * SCH * INNER);
    _Float16* win16  = x16    + (size_t)MROWS * DMODEL;
    _Float16* wout16 = win16  + (size_t)(2 * INNER) * DMODEL;
    _Float16* wssm16 = wout16 + (size_t)DMODEL * INNER;       // 128 x 2048 (padded)
    _Float16* u16raw = wssm16 + (size_t)128 * INNER;          // GEMM1 u-half
    _Float16* gate16 = u16raw + (size_t)MROWS * INNER;
    _Float16* uc16   = gate16 + (size_t)MROWS * INNER;        // conv+silu output
    _Float16* dt16   = uc16   + (size_t)MROWS * INNER;
    _Float16* yg16   = dt16   + (size_t)MROWS * INNER;

    // 0. all fp32->fp16 converts (+ W_ssm zero-pad to 128 rows)
    {
        const int total4 = MROWS * DMODEL / 4 + 2 * INNER * DMODEL / 4 +
                           DMODEL * INNER / 4 + 128 * INNER / 4;
        cvt_all<<<(total4 + 255) / 256, 256, 0, stream>>>(
            x, W_in, W_out, W_ssm, x16, win16, wout16, wssm16);
    }

    // 1. xz = x @ W_in.T -> u16raw | gate16   M=4096 N=4096 K=1024
    //    XCD swizzle: 32 m-blocks, 4 n-subs per XCD
    gemm128<1, 4><<<dim3(1024, 1, 1), 256, 0, stream>>>(
        x16, DMODEL, win16, DMODEL, nullptr, u16raw, gate16,
        0, DMODEL, 0);

    // 2. uc16 = silu(causal_conv(u16raw))
    conv_silu<<<(MROWS * INNER / 4) / 256, 256, 0, stream>>>(
        u16raw, convw, uc16);

    // 3. params partials = uc16 @ wssm16.T  (split-K x8, plain stores)
    gemm128<0, 0><<<dim3(32, 1, 8), 256, 0, stream>>>(
        uc16, INNER, wssm16, INNER, ppart, nullptr, nullptr,
        128, INNER / 8, (size_t)MROWS * 128);
    reduce_params<<<(MROWS * 24 + 255) / 256, 256, 0, stream>>>(ppart, params);

    // 4. dt16 = softplus(d_low @ W_dt.T + b_dt)  M=4096 N=2048 K=64 (lda=96)
    gemm_nt_sp<<<dim3(64, 32), 256, 0, stream>>>(
        params, 96, W_dt, DRANK, dt16, INNER, DRANK, b_dt);

    // 5. chunked selective scan (3 passes); pass3 emits fp16 yg
    scan_pass1<<<BB * (INNER / 256) * SCH, 256, 0, stream>>>(
        uc16, dt16, params, log_A, Hbuf, sumdt);
    scan_pass2<<<BB * INNER * NST / 256, 256, 0, stream>>>(
        Hbuf, sumdt, log_A, hinit);
    scan_pass3<<<BB * (INNER / 256) * SCH, 256, 0, stream>>>(
        uc16, dt16, params, gate16, log_A, Dv, hinit, yg16);

    // 6. out = yg @ W_out.T   M=4096 N=1024 K=2048, no split-K, plain stores
    //    XCD swizzle: 32 m-blocks, 1 n-sub per XCD (B tile pinned in L2)
    gemm128<0, 1><<<dim3(256, 1, 1), 256, 0, stream>>>(
        yg16, INNER, wout16, INNER, out, nullptr, nullptr,
        DMODEL, INNER, 0);
}

// Round 10
// 346.537 us; speedup vs baseline: 1.2910x; 1.0455x over previous
//
#include <hip/hip_runtime.h>
#include <cstdint>
#include <cstddef>

// Problem constants (fixed by setup_inputs)
#define BB     2
#define LL     2048
#define DMODEL 1024
#define INNER  2048
#define NST    16
#define KCONV  4
#define DRANK  64
#define MROWS  (BB*LL)   // 4096
#define SCH    64        // time chunks
#define TCH    (LL/SCH)  // 32 timesteps per chunk

typedef __attribute__((ext_vector_type(8))) _Float16 half8;   // 8 fp16 = 4 VGPRs
typedef __attribute__((ext_vector_type(4))) _Float16 half4;
typedef __attribute__((ext_vector_type(4))) float floatx4;

// async global->LDS, 16B per lane, dest = wave-uniform base + lane*16
#define GLL(gp, lp) __builtin_amdgcn_global_load_lds( \
    (const __attribute__((address_space(1))) unsigned int*)(gp), \
    (__attribute__((address_space(3))) unsigned int*)(lp), 16, 0, 0)

// ---------------------------------------------------------------------------
// One fused convert kernel: x->x16, W_in->win16, W_out->wout16,
// W_ssm->wssm16 zero-padded to 128 rows, W_dt->wdt16.
// ---------------------------------------------------------------------------
__global__ __launch_bounds__(256)
void cvt_all(const float* __restrict__ x, const float* __restrict__ w_in,
             const float* __restrict__ w_out, const float* __restrict__ w_ssm,
             const float* __restrict__ w_dt,
             _Float16* __restrict__ x16, _Float16* __restrict__ win16,
             _Float16* __restrict__ wout16, _Float16* __restrict__ wssm16,
             _Float16* __restrict__ wdt16)
{
    const int idx = blockIdx.x * 256 + threadIdx.x;
    const int R1 = MROWS * DMODEL / 4;            // x
    const int R2 = R1 + 2 * INNER * DMODEL / 4;   // W_in
    const int R3 = R2 + DMODEL * INNER / 4;       // W_out
    const int R4 = R3 + 128 * INNER / 4;          // W_ssm (padded)
    const int R5 = R4 + INNER * DRANK / 4;        // W_dt
    const float* src; _Float16* dst; int i;
    if (idx < R1)      { src = x;     dst = x16;    i = idx; }
    else if (idx < R2) { src = w_in;  dst = win16;  i = idx - R1; }
    else if (idx < R3) { src = w_out; dst = wout16; i = idx - R2; }
    else if (idx < R4) {
        i = idx - R3;                               // over 128x2048/4
        const int row = i / (INNER / 4);
        half4 h = (half4){0, 0, 0, 0};
        if (row < 96) {
            const float4 v = ((const float4*)w_ssm)[i];
            h.x = (_Float16)v.x; h.y = (_Float16)v.y;
            h.z = (_Float16)v.z; h.w = (_Float16)v.w;
        }
        *(half4*)(wssm16 + (size_t)i * 4) = h;
        return;
    }
    else if (idx < R5) { src = w_dt;  dst = wdt16;  i = idx - R4; }
    else return;
    const float4 v = ((const float4*)src)[i];
    half4 h;
    h.x = (_Float16)v.x; h.y = (_Float16)v.y;
    h.z = (_Float16)v.z; h.w = (_Float16)v.w;
    *(half4*)(dst + (size_t)i * 4) = h;
}

// ---------------------------------------------------------------------------
// fp16 MFMA NT-GEMM, 128x128 tile, double-buffered LDS, one barrier/K-iter,
// coalesced GLL staging with XOR chunk swizzle.
// NN8>0: XCD-aware mapping (XCD k owns n_blk % 8 == k, NN8 n-subs).
// EPI 1: cols < INNER -> Cu fp16; else Cg fp16 (both ld INNER)
// EPI 0: plain fp32 store, C += blockIdx.z * zstride
// EPI 3: softplus(v + bias[col]) -> fp16 Cg (ld INNER)
// ---------------------------------------------------------------------------
template<int EPI, int NN8>
__global__ __launch_bounds__(256)
void gemm128(const _Float16* __restrict__ A, int lda,
             const _Float16* __restrict__ B, int ldb,
             float* __restrict__ C, _Float16* __restrict__ Cu,
             _Float16* __restrict__ Cg,
             int ldc, int kchunk, size_t zstride,
             const float* __restrict__ bias)
{
    __shared__ __align__(16) _Float16 sA[2][128 * 32];  // 8 KB each
    __shared__ __align__(16) _Float16 sB[2][128 * 32];

    int m_blk, n_blk;
    if (NN8 > 0) {
        const int xcd = blockIdx.x & 7;
        const int t   = blockIdx.x >> 3;
        const int m_in  = t & 7;
        const int rest  = t >> 3;
        const int n_sub = rest % NN8;
        const int oct   = rest / NN8;
        m_blk = oct * 8 + m_in;
        n_blk = xcd + 8 * n_sub;
    } else {
        m_blk = blockIdx.x;
        n_blk = blockIdx.y;
    }

    const int tid  = threadIdx.x;
    const int w    = tid >> 6;
    const int lane = tid & 63;
    const int ln15 = lane & 15;
    const int q    = lane >> 4;
    const int wm   = w & 1, wn = w >> 1;
    const int m0 = m_blk * 128, n0 = n_blk * 128;
    const int kbeg = blockIdx.z * kchunk;
    if (EPI == 0) C += (size_t)blockIdx.z * zstride;

    floatx4 acc[4][4];
    #pragma unroll
    for (int i = 0; i < 4; ++i)
        #pragma unroll
        for (int j = 0; j < 4; ++j)
            acc[i][j] = (floatx4){0.f, 0.f, 0.f, 0.f};

    const int lr = lane >> 2;
    const int cs = lane & 3;
    const int g0 = 2 * w, g1 = 2 * w + 1;
    const int rt0 = 16 * g0 + lr, rt1 = 16 * g1 + lr;
    const int c0 = cs ^ (rt0 & 3) ^ ((rt0 >> 2) & 3);
    const int c1 = cs ^ (rt1 & 3) ^ ((rt1 >> 2) & 3);
    const size_t ga0 = (size_t)(m0 + rt0) * lda + kbeg + c0 * 8;
    const size_t ga1 = (size_t)(m0 + rt1) * lda + kbeg + c1 * 8;
    const size_t gb0 = (size_t)(n0 + rt0) * ldb + kbeg + c0 * 8;
    const size_t gb1 = (size_t)(n0 + rt1) * ldb + kbeg + c1 * 8;
    const int lo0 = g0 * 512, lo1 = g1 * 512;

    GLL(A + ga0, &sA[0][lo0]);
    GLL(A + ga1, &sA[0][lo1]);
    GLL(B + gb0, &sB[0][lo0]);
    GLL(B + gb1, &sB[0][lo1]);

    const int sw = q ^ (ln15 & 3) ^ ((ln15 >> 2) & 3);

    const int niter = kchunk >> 5;
    for (int i = 0; i < niter; ++i) {
        __syncthreads();
        if (i + 1 < niter) {
            const int kg = (i + 1) * 32;
            const int nb = (i + 1) & 1;
            GLL(A + ga0 + kg, &sA[nb][lo0]);
            GLL(A + ga1 + kg, &sA[nb][lo1]);
            GLL(B + gb0 + kg, &sB[nb][lo0]);
            GLL(B + gb1 + kg, &sB[nb][lo1]);
        }
        const _Float16* bufA = sA[i & 1];
        const _Float16* bufB = sB[i & 1];
        half8 fa[4], fb[4];
        #pragma unroll
        for (int t = 0; t < 4; ++t) {
            fa[t] = *(const half8*)&bufA[(wm * 64 + t * 16 + ln15) * 32 + sw * 8];
            fb[t] = *(const half8*)&bufB[(wn * 64 + t * 16 + ln15) * 32 + sw * 8];
        }
        #pragma unroll
        for (int mt = 0; mt < 4; ++mt)
            #pragma unroll
            for (int nt = 0; nt < 4; ++nt)
                acc[mt][nt] = __builtin_amdgcn_mfma_f32_16x16x32_f16(
                    fa[mt], fb[nt], acc[mt][nt], 0, 0, 0);
    }

    #pragma unroll
    for (int mt = 0; mt < 4; ++mt) {
        const int rowb = m0 + wm * 64 + mt * 16 + q * 4;
        #pragma unroll
        for (int nt = 0; nt < 4; ++nt) {
            const int col = n0 + wn * 64 + nt * 16 + ln15;
            #pragma unroll
            for (int r = 0; r < 4; ++r) {
                const float v = acc[mt][nt][r];
                const size_t row = (size_t)(rowb + r);
                if (EPI == 1) {
                    if (col < INNER) Cu[row * INNER + col] = (_Float16)v;
                    else Cg[row * INNER + (col - INNER)] = (_Float16)v;
                } else if (EPI == 3) {
                    float s = v + bias[col];
                    s = (s > 20.f) ? s : log1pf(__expf(s));
                    Cg[row * INNER + col] = (_Float16)s;
                } else {
                    C[row * ldc + col] = v;
                }
            }
        }
    }
}

// ---------------------------------------------------------------------------
// GEMM2 with fused causal conv+SiLU on the A operand.
// ppart[z][M][128] = conv_silu(u16raw)[M, z*256..z*256+255] @ wssm16[128,:]^T
// A staged manually (conv in registers -> swizzled LDS); B staged via GLL.
// Grid (32, 1, 8), 256 threads.
// ---------------------------------------------------------------------------
__global__ __launch_bounds__(256)
void gemm2_conv(const _Float16* __restrict__ U,     // u16raw [M][INNER]
                const float* __restrict__ conv_w,   // [INNER][4]
                const _Float16* __restrict__ B,     // wssm16 [128][INNER]
                float* __restrict__ ppart)          // [8][M][128]
{
    __shared__ __align__(16) _Float16 sA[2][128 * 32];
    __shared__ __align__(16) _Float16 sB[2][128 * 32];

    const int tid  = threadIdx.x;
    const int w    = tid >> 6;
    const int lane = tid & 63;
    const int ln15 = lane & 15;
    const int q    = lane >> 4;
    const int wm   = w & 1, wn = w >> 1;
    const int m0   = blockIdx.x * 128;
    const int z    = blockIdx.z;
    const int kbeg = z * 256;
    float* Cz = ppart + (size_t)z * MROWS * 128;

    // conv staging assignment: channel cch (0..31), row group rg (0..7)
    const int cch = tid & 31;
    const int rg  = tid >> 5;

    // B staging lane mapping (GLL, as in gemm128)
    const int lr = lane >> 2;
    const int cs = lane & 3;
    const int g0 = 2 * w, g1 = 2 * w + 1;
    const int rt0 = 16 * g0 + lr, rt1 = 16 * g1 + lr;
    const int c0 = cs ^ (rt0 & 3) ^ ((rt0 >> 2) & 3);
    const int c1 = cs ^ (rt1 & 3) ^ ((rt1 >> 2) & 3);
    const size_t gb0 = (size_t)rt0 * INNER + kbeg + c0 * 8;
    const size_t gb1 = (size_t)rt1 * INNER + kbeg + c1 * 8;
    const int lo0 = g0 * 512, lo1 = g1 * 512;

    floatx4 acc[4][4];
    #pragma unroll
    for (int i = 0; i < 4; ++i)
        #pragma unroll
        for (int j = 0; j < 4; ++j)
            acc[i][j] = (floatx4){0.f, 0.f, 0.f, 0.f};

    // stage conv(A) k-window [k0, k0+32) into dst (swizzled layout)
    auto stageA = [&](int k0, _Float16* dst) {
        const int ch = k0 + cch;
        const float4 wv = *(const float4*)(conv_w + (size_t)ch * KCONV);
        const int r0 = m0 + rg * 16;
        float u3 = 0.f, u2 = 0.f, u1 = 0.f;
        if ((r0 & (LL - 1)) != 0) {   // r0 mult of 16 -> t0==0 only at b starts
            u3 = (float)U[(size_t)(r0 - 3) * INNER + ch];
            u2 = (float)U[(size_t)(r0 - 2) * INNER + ch];
            u1 = (float)U[(size_t)(r0 - 1) * INNER + ch];
        }
        #pragma unroll
        for (int rr = 0; rr < 16; ++rr) {
            const float u0 = (float)U[(size_t)(r0 + rr) * INNER + ch];
            const float s = wv.x * u3 + wv.y * u2 + wv.z * u1 + wv.w * u0;
            const float uc = s / (1.f + __expf(-s));
            const int rt = rg * 16 + rr;
            const int slot = (cch >> 3) ^ (rt & 3) ^ ((rt >> 2) & 3);
            dst[rt * 32 + slot * 8 + (cch & 7)] = (_Float16)uc;
            u3 = u2; u2 = u1; u1 = u0;
        }
    };

    // prologue: buffer 0
    stageA(kbeg, sA[0]);
    GLL(B + gb0, &sB[0][lo0]);
    GLL(B + gb1, &sB[0][lo1]);

    const int sw = q ^ (ln15 & 3) ^ ((ln15 >> 2) & 3);

    for (int i = 0; i < 8; ++i) {
        __syncthreads();
        const int nb = (i + 1) & 1;
        if (i + 1 < 8) {
            const int kg = (i + 1) * 32;
            GLL(B + gb0 + kg, &sB[nb][lo0]);
            GLL(B + gb1 + kg, &sB[nb][lo1]);
        }
        const _Float16* bufA = sA[i & 1];
        const _Float16* bufB = sB[i & 1];
        half8 fa[4], fb[4];
        #pragma unroll
        for (int t = 0; t < 4; ++t) {
            fa[t] = *(const half8*)&bufA[(wm * 64 + t * 16 + ln15) * 32 + sw * 8];
            fb[t] = *(const half8*)&bufB[(wn * 64 + t * 16 + ln15) * 32 + sw * 8];
        }
        #pragma unroll
        for (int mt = 0; mt < 4; ++mt)
            #pragma unroll
            for (int nt = 0; nt < 4; ++nt)
                acc[mt][nt] = __builtin_amdgcn_mfma_f32_16x16x32_f16(
                    fa[mt], fb[nt], acc[mt][nt], 0, 0, 0);
        if (i + 1 < 8)
            stageA(kbeg + (i + 1) * 32, sA[nb]);
    }

    #pragma unroll
    for (int mt = 0; mt < 4; ++mt) {
        const int rowb = m0 + wm * 64 + mt * 16 + q * 4;
        #pragma unroll
        for (int nt = 0; nt < 4; ++nt) {
            const int col = wn * 64 + nt * 16 + ln15;
            #pragma unroll
            for (int r = 0; r < 4; ++r)
                Cz[(size_t)(rowb + r) * 128 + col] = acc[mt][nt][r];
        }
    }
}

// ---------------------------------------------------------------------------
// Reduce GEMM2's 8 split-K partials -> params [M][96] and dlow16 [M][64]
// ---------------------------------------------------------------------------
__global__ __launch_bounds__(256)
void reduce_params(const float* __restrict__ part, float* __restrict__ params,
                   _Float16* __restrict__ dlow16)
{
    const int idx = blockIdx.x * 256 + threadIdx.x;   // over MROWS*24
    if (idx >= MROWS * 24) return;
    const int r = idx / 24;
    const int c = (idx - r * 24) * 4;
    float4 s = make_float4(0.f, 0.f, 0.f, 0.f);
    #pragma unroll
    for (int z = 0; z < 8; ++z) {
        const float4 v = *(const float4*)(part + ((size_t)z * MROWS + r) * 128 + c);
        s.x += v.x; s.y += v.y; s.z += v.z; s.w += v.w;
    }
    *(float4*)(params + (size_t)r * 96 + c) = s;
    if (c < DRANK) {
        half4 h;
        h.x = (_Float16)s.x; h.y = (_Float16)s.y;
        h.z = (_Float16)s.z; h.w = (_Float16)s.w;
        *(half4*)(dlow16 + (size_t)r * DRANK + c) = h;
    }
}

// ---------------------------------------------------------------------------
// Scan pass 1: per-chunk summaries, conv+SiLU computed on the fly (rolling
// 4-tap window over u16raw). h[16] in registers per thread-channel.
// ---------------------------------------------------------------------------
__global__ __launch_bounds__(256)
void scan_pass1(const _Float16* __restrict__ U,      // u16raw
                const _Float16* __restrict__ dt16,
                const float* __restrict__ params,
                const float* __restrict__ conv_w,
                const float* __restrict__ log_A,
                float* __restrict__ Hout,
                float* __restrict__ sumdt_out)
{
    const int bid = blockIdx.x;
    const int c   = bid & (SCH - 1);
    const int cg  = (bid >> 6) & 7;
    const int b   = bid >> 9;
    const int tid = threadIdx.x;
    const int d   = cg * 256 + tid;
    const size_t rowbase = (size_t)b * LL + (size_t)c * TCH;

    float A[NST];
    #pragma unroll
    for (int n = 0; n < NST; n += 4) {
        float4 v = *(const float4*)(log_A + (size_t)d * NST + n);
        A[n+0] = -__expf(v.x); A[n+1] = -__expf(v.y);
        A[n+2] = -__expf(v.z); A[n+3] = -__expf(v.w);
    }
    const float4 wv = *(const float4*)(conv_w + (size_t)d * KCONV);
    float u3 = 0.f, u2 = 0.f, u1 = 0.f;
    if (c > 0) {
        u3 = (float)U[(rowbase - 3) * INNER + d];
        u2 = (float)U[(rowbase - 2) * INNER + d];
        u1 = (float)U[(rowbase - 1) * INNER + d];
    }

    __shared__ float Bs[TCH * NST];
    for (int i = tid; i < TCH * NST; i += 256) {
        const int t = i >> 4, j = i & 15;
        Bs[i] = params[(rowbase + t) * 96 + DRANK + j];
    }
    __syncthreads();

    float h[NST];
    #pragma unroll
    for (int n = 0; n < NST; ++n) h[n] = 0.f;
    float sdt = 0.f;

    #pragma unroll 4
    for (int t = 0; t < TCH; ++t) {
        const float dtv = (float)dt16[(rowbase + t) * INNER + d];
        const float u0  = (float)U[(rowbase + t) * INNER + d];
        const float sc = wv.x * u3 + wv.y * u2 + wv.z * u1 + wv.w * u0;
        const float uv = sc / (1.f + __expf(-sc));
        u3 = u2; u2 = u1; u1 = u0;
        const float du = dtv * uv;
        sdt += dtv;
        const float4* Bp = (const float4*)&Bs[t * NST];
        const float4 B0 = Bp[0], B1 = Bp[1], B2 = Bp[2], B3 = Bp[3];
        const float Bv[NST] = {B0.x,B0.y,B0.z,B0.w, B1.x,B1.y,B1.z,B1.w,
                               B2.x,B2.y,B2.z,B2.w, B3.x,B3.y,B3.z,B3.w};
        #pragma unroll
        for (int n = 0; n < NST; ++n)
            h[n] = fmaf(__expf(dtv * A[n]), h[n], du * Bv[n]);
    }

    const size_t o = ((size_t)(b * SCH + c) * INNER + d) * NST;
    #pragma unroll
    for (int n = 0; n < NST; n += 4)
        *(float4*)(Hout + o + n) = make_float4(h[n], h[n+1], h[n+2], h[n+3]);
    sumdt_out[(size_t)(b * SCH + c) * INNER + d] = sdt;
}

// ---------------------------------------------------------------------------
// Scan pass 2: serial combine over chunks. One thread = one (b,d,n).
// ---------------------------------------------------------------------------
__global__ __launch_bounds__(256)
void scan_pass2(const float* __restrict__ Hbuf,
                const float* __restrict__ sumdt,
                const float* __restrict__ log_A,
                float* __restrict__ hinit)
{
    const int idx = blockIdx.x * 256 + threadIdx.x;
    const int n = idx & 15;
    const int d = (idx >> 4) & (INNER - 1);
    const int b = idx >> 15;
    const float An = -__expf(log_A[(size_t)d * NST + n]);
    float h = 0.f;
    for (int c = 0; c < SCH; ++c) {
        const size_t o = ((size_t)(b * SCH + c) * INNER + d) * NST + n;
        hinit[o] = h;
        const float P = __expf(An * sumdt[(size_t)(b * SCH + c) * INNER + d]);
        h = Hbuf[o] + P * h;
    }
}

// ---------------------------------------------------------------------------
// Scan pass 3: re-scan from h_init with on-the-fly conv+SiLU; fused epilogue
// yg = (y + u*D) * silu(gate) -> fp16.
// ---------------------------------------------------------------------------
__global__ __launch_bounds__(256)
void scan_pass3(const _Float16* __restrict__ U,      // u16raw
                const _Float16* __restrict__ dt16,
                const float* __restrict__ params,
                const float* __restrict__ conv_w,
                const _Float16* __restrict__ gate16,
                const float* __restrict__ log_A,
                const float* __restrict__ Dv,
                const float* __restrict__ hinit,
                _Float16* __restrict__ yg16)
{
    const int bid = blockIdx.x;
    const int c   = bid & (SCH - 1);
    const int cg  = (bid >> 6) & 7;
    const int b   = bid >> 9;
    const int tid = threadIdx.x;
    const int d   = cg * 256 + tid;
    const size_t rowbase = (size_t)b * LL + (size_t)c * TCH;

    float A[NST];
    #pragma unroll
    for (int n = 0; n < NST; n += 4) {
        float4 v = *(const float4*)(log_A + (size_t)d * NST + n);
        A[n+0] = -__expf(v.x); A[n+1] = -__expf(v.y);
        A[n+2] = -__expf(v.z); A[n+3] = -__expf(v.w);
    }
    const float Dd = Dv[d];
    const float4 wv = *(const float4*)(conv_w + (size_t)d * KCONV);
    float u3 = 0.f, u2 = 0.f, u1 = 0.f;
    if (c > 0) {
        u3 = (float)U[(rowbase - 3) * INNER + d];
        u2 = (float)U[(rowbase - 2) * INNER + d];
        u1 = (float)U[(rowbase - 1) * INNER + d];
    }

    __shared__ float BCs[TCH * 32];
    for (int i = tid; i < TCH * 32; i += 256) {
        const int t = i >> 5, j = i & 31;
        BCs[i] = params[(rowbase + t) * 96 + DRANK + j];
    }

    float h[NST];
    {
        const size_t o = ((size_t)(b * SCH + c) * INNER + d) * NST;
        #pragma unroll
        for (int n = 0; n < NST; n += 4) {
            float4 v = *(const float4*)(hinit + o + n);
            h[n] = v.x; h[n+1] = v.y; h[n+2] = v.z; h[n+3] = v.w;
        }
    }
    __syncthreads();

    #pragma unroll 2
    for (int t = 0; t < TCH; ++t) {
        const float dtv = (float)dt16[(rowbase + t) * INNER + d];
        const float u0  = (float)U[(rowbase + t) * INNER + d];
        const float gv  = (float)gate16[(rowbase + t) * INNER + d];
        const float sc = wv.x * u3 + wv.y * u2 + wv.z * u1 + wv.w * u0;
        const float uv = sc / (1.f + __expf(-sc));
        u3 = u2; u2 = u1; u1 = u0;
        const float du = dtv * uv;
        const float4* Bp = (const float4*)&BCs[t * 32];
        const float4 B0 = Bp[0], B1 = Bp[1], B2 = Bp[2], B3 = Bp[3];
        const float4 C0 = Bp[4], C1 = Bp[5], C2 = Bp[6], C3 = Bp[7];
        const float Bv[NST] = {B0.x,B0.y,B0.z,B0.w, B1.x,B1.y,B1.z,B1.w,
                               B2.x,B2.y,B2.z,B2.w, B3.x,B3.y,B3.z,B3.w};
        const float Cv[NST] = {C0.x,C0.y,C0.z,C0.w, C1.x,C1.y,C1.z,C1.w,
                               C2.x,C2.y,C2.z,C2.w, C3.x,C3.y,C3.z,C3.w};
        #pragma unroll
        for (int n = 0; n < NST; ++n)
            h[n] = fmaf(__expf(dtv * A[n]), h[n], du * Bv[n]);
        float p[8];
        #pragma unroll
        for (int n = 0; n < 8; ++n)
            p[n] = fmaf(h[n], Cv[n], h[n+8] * Cv[n+8]);
        const float y = ((p[0]+p[1]) + (p[2]+p[3])) + ((p[4]+p[5]) + (p[6]+p[7]));
        const float sg = gv / (1.f + __expf(-gv));
        yg16[(rowbase + t) * INNER + d] = (_Float16)((y + uv * Dd) * sg);
    }
}

// ---------------------------------------------------------------------------
extern "C" void kernel_launch(void* const* d_in, const int* in_sizes, int n_in,
                              void* d_out, int out_size, void* d_ws, size_t ws_size,
                              hipStream_t stream)
{
    const float* x     = (const float*)d_in[0];
    const float* W_in  = (const float*)d_in[1];
    const float* convw = (const float*)d_in[2];
    const float* W_ssm = (const float*)d_in[3];
    const float* W_dt  = (const float*)d_in[4];
    const float* b_dt  = (const float*)d_in[5];
    const float* log_A = (const float*)d_in[6];
    const float* Dv    = (const float*)d_in[7];
    const float* W_out = (const float*)d_in[8];
    float* out = (float*)d_out;

    float* ws = (float*)d_ws;
    float* params = ws;                                       // 4096*96
    float* ppart  = params + (size_t)MROWS * 96;              // 8*4096*128
    float* Hbuf   = ppart  + (size_t)8 * MROWS * 128;
    float* hinit  = Hbuf   + (size_t)BB * SCH * INNER * NST;
    float* sumdt  = hinit  + (size_t)BB * SCH * INNER * NST;
    _Float16* x16    = (_Float16*)(sumdt + (size_t)BB * SCH * INNER);
    _Float16* win16  = x16    + (size_t)MROWS * DMODEL;
    _Float16* wout16 = win16  + (size_t)(2 * INNER) * DMODEL;
    _Float16* wssm16 = wout16 + (size_t)DMODEL * INNER;       // 128 x 2048
    _Float16* wdt16  = wssm16 + (size_t)128 * INNER;          // 2048 x 64
    _Float16* dlow16 = wdt16  + (size_t)INNER * DRANK;        // 4096 x 64
    _Float16* u16raw = dlow16 + (size_t)MROWS * DRANK;
    _Float16* gate16 = u16raw + (size_t)MROWS * INNER;
    _Float16* dt16   = gate16 + (size_t)MROWS * INNER;
    _Float16* yg16   = dt16   + (size_t)MROWS * INNER;

    // 0. all fp32->fp16 converts
    {
        const int total4 = MROWS * DMODEL / 4 + 2 * INNER * DMODEL / 4 +
                           DMODEL * INNER / 4 + 128 * INNER / 4 +
                           INNER * DRANK / 4;
        cvt_all<<<(total4 + 255) / 256, 256, 0, stream>>>(
            x, W_in, W_out, W_ssm, W_dt, x16, win16, wout16, wssm16, wdt16);
    }

    // 1. xz = x @ W_in.T -> u16raw | gate16   M=4096 N=4096 K=1024
    gemm128<1, 4><<<dim3(1024, 1, 1), 256, 0, stream>>>(
        x16, DMODEL, win16, DMODEL, nullptr, u16raw, gate16,
        0, DMODEL, 0, nullptr);

    // 2. params partials = conv_silu(u16raw) @ wssm16.T (split-K x8, fused conv)
    gemm2_conv<<<dim3(32, 1, 8), 256, 0, stream>>>(
        u16raw, convw, wssm16, ppart);
    reduce_params<<<(MROWS * 24 + 255) / 256, 256, 0, stream>>>(
        ppart, params, dlow16);

    // 3. dt16 = softplus(dlow16 @ wdt16.T + b_dt)  M=4096 N=2048 K=64 (MFMA)
    gemm128<3, 0><<<dim3(32, 16, 1), 256, 0, stream>>>(
        dlow16, DRANK, wdt16, DRANK, nullptr, nullptr, dt16,
        0, DRANK, 0, b_dt);

    // 4. chunked selective scan (3 passes, conv fused into 1 & 3)
    scan_pass1<<<BB * (INNER / 256) * SCH, 256, 0, stream>>>(
        u16raw, dt16, params, convw, log_A, Hbuf, sumdt);
    scan_pass2<<<BB * INNER * NST / 256, 256, 0, stream>>>(
        Hbuf, sumdt, log_A, hinit);
    scan_pass3<<<BB * (INNER / 256) * SCH, 256, 0, stream>>>(
        u16raw, dt16, params, convw, gate16, log_A, Dv, hinit, yg16);

    // 5. out = yg @ W_out.T   M=4096 N=1024 K=2048, plain stores
    gemm128<0, 1><<<dim3(256, 1, 1), 256, 0, stream>>>(
        yg16, INNER, wout16, INNER, out, nullptr, nullptr,
        DMODEL, INNER, 0, nullptr);
}